// Round 3
// baseline (1049.927 us; speedup 1.0000x reference)
//
#include <hip/hip_runtime.h>

#define NN 50000
#define NE 625000
#define IND 512
#define HID 128
#define OUTD 40
#define NL 3

typedef short v8s __attribute__((ext_vector_type(8)));
typedef float v4f __attribute__((ext_vector_type(4)));

__device__ inline ushort f2bf(float x) {
    unsigned u = __float_as_uint(x);
    u += 0x7FFF + ((u >> 16) & 1);  // RNE
    return (ushort)(u >> 16);
}
__device__ inline float bf2f(ushort b) { return __uint_as_float(((unsigned)b) << 16); }

// ---------------- CSR build ----------------

__global__ __launch_bounds__(256) void count_kernel(const int* __restrict__ dst,
                                                    int* __restrict__ deg) {
    int e = blockIdx.x * 256 + threadIdx.x;
    if (e < NE) atomicAdd(&deg[dst[e]], 1);
}

__global__ __launch_bounds__(1024) void scan_kernel(const int* __restrict__ deg,
                                                    int* __restrict__ rp,
                                                    int* __restrict__ cursor) {
    __shared__ int sums[1024];
    const int CH = (NN + 1023) / 1024;  // 49
    int t = threadIdx.x;
    int beg = t * CH;
    int end = beg + CH < NN ? beg + CH : NN;
    int s = 0;
    for (int i = beg; i < end; i++) s += deg[i];
    sums[t] = s;
    __syncthreads();
    for (int off = 1; off < 1024; off <<= 1) {
        int v = (t >= off) ? sums[t - off] : 0;
        __syncthreads();
        sums[t] += v;
        __syncthreads();
    }
    int run = sums[t] - s;  // exclusive prefix
    for (int i = beg; i < end; i++) {
        rp[i] = run;
        cursor[i] = run;
        run += deg[i];
    }
    if (t == 1023) rp[NN] = run;
}

__global__ __launch_bounds__(256) void fill_kernel(const int* __restrict__ src,
                                                   const int* __restrict__ dst,
                                                   const float* __restrict__ ew,
                                                   int* __restrict__ cursor,
                                                   int* __restrict__ csr_src,
                                                   float* __restrict__ csr_w) {
    int e = blockIdx.x * 256 + threadIdx.x;
    if (e < NE) {
        int d = dst[e];
        int pos = atomicAdd(&cursor[d], 1);
        csr_src[pos] = src[e];
        csr_w[pos] = ew[e];
    }
}

// ---------------- weight split+transpose: W[k][c] f32 -> Wt[c][k] bf16 hi/lo ----------------

__global__ __launch_bounds__(256) void conv_emb(const float* __restrict__ W,
                                                ushort* __restrict__ Th,
                                                ushort* __restrict__ Tl) {
    int f = blockIdx.x * 256 + threadIdx.x;  // 16384 float4s
    int k = f >> 5;
    int c0 = (f & 31) * 4;
    float4 v = *reinterpret_cast<const float4*>(W + (size_t)k * HID + c0);
    float vv[4] = {v.x, v.y, v.z, v.w};
#pragma unroll
    for (int i = 0; i < 4; i++) {
        ushort h = f2bf(vv[i]);
        ushort l = f2bf(vv[i] - bf2f(h));
        Th[(size_t)(c0 + i) * IND + k] = h;
        Tl[(size_t)(c0 + i) * IND + k] = l;
    }
}

__global__ __launch_bounds__(256) void conv_mlp(const float* __restrict__ W1,
                                                const float* __restrict__ W2,
                                                ushort* __restrict__ T1h, ushort* __restrict__ T1l,
                                                ushort* __restrict__ T2h, ushort* __restrict__ T2l) {
    int mat = blockIdx.x >> 4;  // 0..5
    int lay = mat >> 1;
    const float* src = ((mat & 1) ? W2 : W1) + (size_t)lay * HID * HID;
    ushort* dh = ((mat & 1) ? T2h : T1h) + (size_t)lay * HID * HID;
    ushort* dl = ((mat & 1) ? T2l : T1l) + (size_t)lay * HID * HID;
    int f = (blockIdx.x & 15) * 256 + threadIdx.x;  // 4096 float4 per mat
    int k = f >> 5;
    int c0 = (f & 31) * 4;
    float4 v = *reinterpret_cast<const float4*>(src + (size_t)k * HID + c0);
    float vv[4] = {v.x, v.y, v.z, v.w};
#pragma unroll
    for (int i = 0; i < 4; i++) {
        ushort h = f2bf(vv[i]);
        ushort l = f2bf(vv[i] - bf2f(h));
        dh[(size_t)(c0 + i) * HID + k] = h;
        dl[(size_t)(c0 + i) * HID + k] = l;
    }
}

// ---------------- Embedding GEMM (split-bf16 MFMA): [NN,512]@[512,128]+b ----------------
// 512 thr = 8 waves; BM=128 (16 rows/wave); K chunks of 64; no barriers
// (each wave stages and reads only its own 16-row LDS slice).

__global__ __launch_bounds__(512) void emb_mfma(const float* __restrict__ X,
                                                const ushort* __restrict__ Wh,
                                                const ushort* __restrict__ Wl,
                                                const float* __restrict__ B,
                                                float* __restrict__ H) {
    __shared__ __align__(16) ushort Xh[128 * 64];
    __shared__ __align__(16) ushort Xl[128 * 64];
    const int tid = threadIdx.x;
    const int wid = tid >> 6, lane = tid & 63;
    const int lane15 = lane & 15, kg = (lane >> 4) * 8;
    const int brow = blockIdx.x * 128;

    v4f acc[8];
#pragma unroll
    for (int i = 0; i < 8; i++) acc[i] = (v4f)0.f;

    const int rowl = wid * 16 + lane15;
    const int sw = (rowl & 7) << 3;

    for (int k0 = 0; k0 < IND; k0 += 64) {
        // stage own 16 rows x 64 k (f32 -> bf16 hi/lo, XOR-swizzled)
#pragma unroll
        for (int j = 0; j < 4; j++) {
            int f = lane + j * 64;
            int rl = wid * 16 + (f >> 4);
            int ku = (f & 15) * 4;
            int g = brow + rl;
            float4 v = make_float4(0.f, 0.f, 0.f, 0.f);
            if (g < NN) v = *reinterpret_cast<const float4*>(X + (size_t)g * IND + k0 + ku);
            float vv[4] = {v.x, v.y, v.z, v.w};
            ushort hh[4], ll[4];
#pragma unroll
            for (int i = 0; i < 4; i++) {
                hh[i] = f2bf(vv[i]);
                ll[i] = f2bf(vv[i] - bf2f(hh[i]));
            }
            int idx = rl * 64 + (ku ^ ((rl & 7) << 3));
            *reinterpret_cast<ushort4*>(&Xh[idx]) = make_ushort4(hh[0], hh[1], hh[2], hh[3]);
            *reinterpret_cast<ushort4*>(&Xl[idx]) = make_ushort4(ll[0], ll[1], ll[2], ll[3]);
        }
        // A fragments (own rows only; LDS in-order per wave, no barrier)
        v8s ah[2], al[2];
#pragma unroll
        for (int ks = 0; ks < 2; ks++) {
            int idx = rowl * 64 + ((ks * 32 + kg) ^ sw);
            ah[ks] = *reinterpret_cast<const v8s*>(&Xh[idx]);
            al[ks] = *reinterpret_cast<const v8s*>(&Xl[idx]);
        }
#pragma unroll
        for (int nf = 0; nf < 8; nf++) {
            const ushort* bp = Wh + (size_t)(nf * 16 + lane15) * IND + k0 + kg;
            const ushort* bq = Wl + (size_t)(nf * 16 + lane15) * IND + k0 + kg;
            v4f a = acc[nf];
#pragma unroll
            for (int ks = 0; ks < 2; ks++) {
                v8s bh = *reinterpret_cast<const v8s*>(bp + ks * 32);
                v8s bl = *reinterpret_cast<const v8s*>(bq + ks * 32);
                a = __builtin_amdgcn_mfma_f32_16x16x32_bf16(ah[ks], bh, a, 0, 0, 0);
                a = __builtin_amdgcn_mfma_f32_16x16x32_bf16(al[ks], bh, a, 0, 0, 0);
                a = __builtin_amdgcn_mfma_f32_16x16x32_bf16(ah[ks], bl, a, 0, 0, 0);
            }
            acc[nf] = a;
        }
    }
#pragma unroll
    for (int nf = 0; nf < 8; nf++) {
        int col = nf * 16 + lane15;
        float bias = B[col];
#pragma unroll
        for (int r = 0; r < 4; r++) {
            int g = brow + wid * 16 + (lane >> 4) * 4 + r;
            if (g < NN) H[(size_t)g * HID + col] = acc[nf][r] + bias;
        }
    }
}

// ---------------- Aggregation: z = h + sum w*h[src] (CSR, no atomics) ----------------

__global__ __launch_bounds__(256) void agg_kernel(const float* __restrict__ h,
                                                  const int* __restrict__ rp,
                                                  const int* __restrict__ cs,
                                                  const float* __restrict__ cw,
                                                  float* __restrict__ z) {
    const int node = blockIdx.x * 2 + (threadIdx.x >> 7);
    const int c = threadIdx.x & 127;
    float acc = h[(size_t)node * HID + c];
    int k = rp[node];
    const int ke = rp[node + 1];
    for (; k < ke; k++) {
        int s = cs[k];
        float w = cw[k];
        acc = fmaf(w, h[(size_t)s * HID + c], acc);
    }
    z[(size_t)node * HID + c] = acc;
}

// ---------------- Fused MLP (split-bf16 MFMA): h = relu(relu(z@W1+b1)@W2+b2) ----------------
// 512 thr = 8 waves; BM=128; zero barriers (waves own disjoint 16-row slices).

__global__ __launch_bounds__(512) void mlp_mfma(const float* __restrict__ Z,
                                                const ushort* __restrict__ W1h, const ushort* __restrict__ W1l,
                                                const float* __restrict__ B1,
                                                const ushort* __restrict__ W2h, const ushort* __restrict__ W2l,
                                                const float* __restrict__ B2,
                                                float* __restrict__ H) {
    __shared__ __align__(16) ushort Ah[128 * 128];
    __shared__ __align__(16) ushort Al[128 * 128];
    const int tid = threadIdx.x;
    const int wid = tid >> 6, lane = tid & 63;
    const int lane15 = lane & 15, kg = (lane >> 4) * 8;
    const int brow = blockIdx.x * 128;
    const int rowl = wid * 16 + lane15;
    const int sw = (rowl & 7) << 3;

    // stage z (own 16 rows x 128 k)
#pragma unroll
    for (int j = 0; j < 8; j++) {
        int f = lane + j * 64;
        int rl = wid * 16 + (f >> 5);
        int ku = (f & 31) * 4;
        int g = brow + rl;
        float4 v = make_float4(0.f, 0.f, 0.f, 0.f);
        if (g < NN) v = *reinterpret_cast<const float4*>(Z + (size_t)g * HID + ku);
        float vv[4] = {v.x, v.y, v.z, v.w};
        ushort hh[4], ll[4];
#pragma unroll
        for (int i = 0; i < 4; i++) {
            hh[i] = f2bf(vv[i]);
            ll[i] = f2bf(vv[i] - bf2f(hh[i]));
        }
        int idx = rl * 128 + (ku ^ ((rl & 7) << 3));
        *reinterpret_cast<ushort4*>(&Ah[idx]) = make_ushort4(hh[0], hh[1], hh[2], hh[3]);
        *reinterpret_cast<ushort4*>(&Al[idx]) = make_ushort4(ll[0], ll[1], ll[2], ll[3]);
    }

    v4f acc[8];
#pragma unroll
    for (int i = 0; i < 8; i++) acc[i] = (v4f)0.f;

    v8s ah[4], al[4];
#pragma unroll
    for (int ks = 0; ks < 4; ks++) {
        int idx = rowl * 128 + ((ks * 32 + kg) ^ sw);
        ah[ks] = *reinterpret_cast<const v8s*>(&Ah[idx]);
        al[ks] = *reinterpret_cast<const v8s*>(&Al[idx]);
    }
    // GEMM1: hidden = z @ W1
#pragma unroll
    for (int nf = 0; nf < 8; nf++) {
        const ushort* bp = W1h + (size_t)(nf * 16 + lane15) * HID + kg;
        const ushort* bq = W1l + (size_t)(nf * 16 + lane15) * HID + kg;
        v4f a = acc[nf];
#pragma unroll
        for (int ks = 0; ks < 4; ks++) {
            v8s bh = *reinterpret_cast<const v8s*>(bp + ks * 32);
            v8s bl = *reinterpret_cast<const v8s*>(bq + ks * 32);
            a = __builtin_amdgcn_mfma_f32_16x16x32_bf16(ah[ks], bh, a, 0, 0, 0);
            a = __builtin_amdgcn_mfma_f32_16x16x32_bf16(al[ks], bh, a, 0, 0, 0);
            a = __builtin_amdgcn_mfma_f32_16x16x32_bf16(ah[ks], bl, a, 0, 0, 0);
        }
        acc[nf] = a;
    }
    // bias + relu -> split back into own LDS slice (hidden[row][k=col])
#pragma unroll
    for (int nf = 0; nf < 8; nf++) {
        int col = nf * 16 + lane15;
        float b = B1[col];
#pragma unroll
        for (int r = 0; r < 4; r++) {
            int rl2 = wid * 16 + (lane >> 4) * 4 + r;
            float v = acc[nf][r] + b;
            v = v > 0.f ? v : 0.f;
            ushort h = f2bf(v);
            ushort l = f2bf(v - bf2f(h));
            int idx = rl2 * 128 + (col ^ ((rl2 & 7) << 3));
            Ah[idx] = h;
            Al[idx] = l;
        }
        acc[nf] = (v4f)0.f;
    }
    // reload A fragments (now hidden)
#pragma unroll
    for (int ks = 0; ks < 4; ks++) {
        int idx = rowl * 128 + ((ks * 32 + kg) ^ sw);
        ah[ks] = *reinterpret_cast<const v8s*>(&Ah[idx]);
        al[ks] = *reinterpret_cast<const v8s*>(&Al[idx]);
    }
    // GEMM2: out = hidden @ W2
#pragma unroll
    for (int nf = 0; nf < 8; nf++) {
        const ushort* bp = W2h + (size_t)(nf * 16 + lane15) * HID + kg;
        const ushort* bq = W2l + (size_t)(nf * 16 + lane15) * HID + kg;
        v4f a = acc[nf];
#pragma unroll
        for (int ks = 0; ks < 4; ks++) {
            v8s bh = *reinterpret_cast<const v8s*>(bp + ks * 32);
            v8s bl = *reinterpret_cast<const v8s*>(bq + ks * 32);
            a = __builtin_amdgcn_mfma_f32_16x16x32_bf16(ah[ks], bh, a, 0, 0, 0);
            a = __builtin_amdgcn_mfma_f32_16x16x32_bf16(al[ks], bh, a, 0, 0, 0);
            a = __builtin_amdgcn_mfma_f32_16x16x32_bf16(ah[ks], bl, a, 0, 0, 0);
        }
        acc[nf] = a;
    }
#pragma unroll
    for (int nf = 0; nf < 8; nf++) {
        int col = nf * 16 + lane15;
        float b = B2[col];
#pragma unroll
        for (int r = 0; r < 4; r++) {
            int g = brow + wid * 16 + (lane >> 4) * 4 + r;
            if (g < NN) H[(size_t)g * HID + col] = fmaxf(acc[nf][r] + b, 0.f);
        }
    }
}

// ---------------- Readout: out = h @ roW + rob ----------------

__global__ __launch_bounds__(256) void readout_kernel(const float* __restrict__ h,
                                                      const float* __restrict__ W,
                                                      const float* __restrict__ B,
                                                      float* __restrict__ out) {
    __shared__ float Ws[HID * OUTD];
    __shared__ float Hr[4][HID];
    const int tid = threadIdx.x;
    const int wave = tid >> 6, lane = tid & 63;
    const int rbase = blockIdx.x * 4;
#pragma unroll
    for (int j = 0; j < 5; j++) {
        int f = tid + j * 256;
        reinterpret_cast<float4*>(Ws)[f] = reinterpret_cast<const float4*>(W)[f];
    }
    if (tid < 128) {
        int r = tid >> 5;
        int c4 = (tid & 31) << 2;
        *reinterpret_cast<float4*>(&Hr[r][c4]) =
            *reinterpret_cast<const float4*>(h + (size_t)(rbase + r) * HID + c4);
    }
    __syncthreads();
    const int row = rbase + wave;
    if (lane < OUTD) {
        float acc = B[lane];
#pragma unroll
        for (int k = 0; k < HID; k++) acc = fmaf(Hr[wave][k], Ws[k * OUTD + lane], acc);
        out[(size_t)row * OUTD + lane] = acc;
    }
}

// ---------------- launch ----------------

extern "C" void kernel_launch(void* const* d_in, const int* in_sizes, int n_in,
                              void* d_out, int out_size, void* d_ws, size_t ws_size,
                              hipStream_t stream) {
    const float* features = (const float*)d_in[0];
    const int* src = (const int*)d_in[1];
    const int* dst = (const int*)d_in[2];
    const float* ew = (const float*)d_in[3];
    const float* embW = (const float*)d_in[4];
    const float* embB = (const float*)d_in[5];
    const float* W1 = (const float*)d_in[6];
    const float* B1 = (const float*)d_in[7];
    const float* W2 = (const float*)d_in[8];
    const float* B2 = (const float*)d_in[9];
    const float* roW = (const float*)d_in[10];
    const float* roB = (const float*)d_in[11];
    float* out = (float*)d_out;

    float* h = (float*)d_ws;                           // NN*HID
    float* z = h + (size_t)NN * HID;                   // NN*HID
    int* rp = (int*)(z + (size_t)NN * HID);            // NN+16 (padded for 16B alignment)
    int* cursor = rp + NN + 16;                        // NN
    int* deg = cursor + NN;                            // NN
    int* csr_src = deg + NN;                           // NE
    float* csr_w = (float*)(csr_src + NE);             // NE
    ushort* embWt_h = (ushort*)(csr_w + NE);           // IND*HID
    ushort* embWt_l = embWt_h + (size_t)IND * HID;
    ushort* W1t_h = embWt_l + (size_t)IND * HID;       // NL*HID*HID each
    ushort* W1t_l = W1t_h + (size_t)NL * HID * HID;
    ushort* W2t_h = W1t_l + (size_t)NL * HID * HID;
    ushort* W2t_l = W2t_h + (size_t)NL * HID * HID;

    conv_emb<<<64, 256, 0, stream>>>(embW, embWt_h, embWt_l);
    conv_mlp<<<96, 256, 0, stream>>>(W1, W2, W1t_h, W1t_l, W2t_h, W2t_l);

    hipMemsetAsync(deg, 0, NN * sizeof(int), stream);
    count_kernel<<<(NE + 255) / 256, 256, 0, stream>>>(dst, deg);
    scan_kernel<<<1, 1024, 0, stream>>>(deg, rp, cursor);
    fill_kernel<<<(NE + 255) / 256, 256, 0, stream>>>(src, dst, ew, cursor, csr_src, csr_w);

    emb_mfma<<<(NN + 127) / 128, 512, 0, stream>>>(features, embWt_h, embWt_l, embB, h);

    for (int l = 0; l < NL; l++) {
        agg_kernel<<<NN / 2, 256, 0, stream>>>(h, rp, csr_src, csr_w, z);
        mlp_mfma<<<(NN + 127) / 128, 512, 0, stream>>>(
            z, W1t_h + (size_t)l * HID * HID, W1t_l + (size_t)l * HID * HID,
            B1 + (size_t)l * HID,
            W2t_h + (size_t)l * HID * HID, W2t_l + (size_t)l * HID * HID,
            B2 + (size_t)l * HID, h);
    }

    readout_kernel<<<NN / 4, 256, 0, stream>>>(h, roW, roB, out);
}

// Round 4
// 818.600 us; speedup vs baseline: 1.2826x; 1.2826x over previous
//
#include <hip/hip_runtime.h>

#define NN 50000
#define NE 625000
#define IND 512
#define HID 128
#define OUTD 40
#define NL 3

typedef short v8s __attribute__((ext_vector_type(8)));
typedef float v4f __attribute__((ext_vector_type(4)));

__device__ inline ushort f2bf(float x) {
    unsigned u = __float_as_uint(x);
    u += 0x7FFF + ((u >> 16) & 1);  // RNE
    return (ushort)(u >> 16);
}
__device__ inline float bf2f(ushort b) { return __uint_as_float(((unsigned)b) << 16); }

// split 8 f32 (two float4) into hi/lo bf16 v8s fragments
__device__ inline void split8(float4 a, float4 b, v8s& hi, v8s& lo) {
    float v[8] = {a.x, a.y, a.z, a.w, b.x, b.y, b.z, b.w};
    v8s h, l;
#pragma unroll
    for (int i = 0; i < 8; i++) {
        ushort hu = f2bf(v[i]);
        h[i] = (short)hu;
        l[i] = (short)f2bf(v[i] - bf2f(hu));
    }
    hi = h;
    lo = l;
}

// ---------------- CSR build ----------------

__global__ __launch_bounds__(256) void count_kernel(const int* __restrict__ dst,
                                                    int* __restrict__ deg) {
    int e = blockIdx.x * 256 + threadIdx.x;
    if (e < NE) atomicAdd(&deg[dst[e]], 1);
}

__global__ __launch_bounds__(1024) void scan_kernel(const int* __restrict__ deg,
                                                    int* __restrict__ rp,
                                                    int* __restrict__ cursor) {
    __shared__ int sums[1024];
    const int CH = (NN + 1023) / 1024;  // 49
    int t = threadIdx.x;
    int beg = t * CH;
    int end = beg + CH < NN ? beg + CH : NN;
    int s = 0;
    for (int i = beg; i < end; i++) s += deg[i];
    sums[t] = s;
    __syncthreads();
    for (int off = 1; off < 1024; off <<= 1) {
        int v = (t >= off) ? sums[t - off] : 0;
        __syncthreads();
        sums[t] += v;
        __syncthreads();
    }
    int run = sums[t] - s;  // exclusive prefix
    for (int i = beg; i < end; i++) {
        rp[i] = run;
        cursor[i] = run;
        run += deg[i];
    }
    if (t == 1023) rp[NN] = run;
}

__global__ __launch_bounds__(256) void fill_kernel(const int* __restrict__ src,
                                                   const int* __restrict__ dst,
                                                   const float* __restrict__ ew,
                                                   int* __restrict__ cursor,
                                                   int* __restrict__ csr_src,
                                                   float* __restrict__ csr_w) {
    int e = blockIdx.x * 256 + threadIdx.x;
    if (e < NE) {
        int d = dst[e];
        int pos = atomicAdd(&cursor[d], 1);
        csr_src[pos] = src[e];
        csr_w[pos] = ew[e];
    }
}

// ---------------- weight split+transpose: W[k][c] f32 -> Wt[c][k] bf16 hi/lo ----------------

__global__ __launch_bounds__(256) void conv_emb(const float* __restrict__ W,
                                                ushort* __restrict__ Th,
                                                ushort* __restrict__ Tl) {
    int f = blockIdx.x * 256 + threadIdx.x;  // 16384 float4s
    int k = f >> 5;
    int c0 = (f & 31) * 4;
    float4 v = *reinterpret_cast<const float4*>(W + (size_t)k * HID + c0);
    float vv[4] = {v.x, v.y, v.z, v.w};
#pragma unroll
    for (int i = 0; i < 4; i++) {
        ushort h = f2bf(vv[i]);
        ushort l = f2bf(vv[i] - bf2f(h));
        Th[(size_t)(c0 + i) * IND + k] = h;
        Tl[(size_t)(c0 + i) * IND + k] = l;
    }
}

__global__ __launch_bounds__(256) void conv_mlp(const float* __restrict__ W1,
                                                const float* __restrict__ W2,
                                                ushort* __restrict__ T1h, ushort* __restrict__ T1l,
                                                ushort* __restrict__ T2h, ushort* __restrict__ T2l) {
    int mat = blockIdx.x >> 4;  // 0..5
    int lay = mat >> 1;
    const float* src = ((mat & 1) ? W2 : W1) + (size_t)lay * HID * HID;
    ushort* dh = ((mat & 1) ? T2h : T1h) + (size_t)lay * HID * HID;
    ushort* dl = ((mat & 1) ? T2l : T1l) + (size_t)lay * HID * HID;
    int f = (blockIdx.x & 15) * 256 + threadIdx.x;  // 4096 float4 per mat
    int k = f >> 5;
    int c0 = (f & 31) * 4;
    float4 v = *reinterpret_cast<const float4*>(src + (size_t)k * HID + c0);
    float vv[4] = {v.x, v.y, v.z, v.w};
#pragma unroll
    for (int i = 0; i < 4; i++) {
        ushort h = f2bf(vv[i]);
        ushort l = f2bf(vv[i] - bf2f(h));
        dh[(size_t)(c0 + i) * HID + k] = h;
        dl[(size_t)(c0 + i) * HID + k] = l;
    }
}

// readout W [128][40] f32 -> padded transposed [48][128] bf16 hi/lo
__global__ __launch_bounds__(256) void conv_ro(const float* __restrict__ W,
                                               ushort* __restrict__ Th,
                                               ushort* __restrict__ Tl) {
    int idx = blockIdx.x * 256 + threadIdx.x;  // 48*128 = 6144
    int c = idx >> 7;
    int kk = idx & 127;
    float v = (c < OUTD) ? W[(size_t)kk * OUTD + c] : 0.f;
    ushort h = f2bf(v);
    Th[idx] = h;
    Tl[idx] = f2bf(v - bf2f(h));
}

// ---------------- Embedding GEMM (split-bf16 MFMA, no LDS): [NN,512]@[512,128]+b ----------------
// 256 thr = 4 waves; BM=64 (16 rows/wave); A-fragments loaded directly from
// global into registers (f32 -> bf16 hi/lo), 1-chunk register prefetch.

__global__ __launch_bounds__(256, 3) void emb_mfma(const float* __restrict__ X,
                                                   const ushort* __restrict__ Wh,
                                                   const ushort* __restrict__ Wl,
                                                   const float* __restrict__ B,
                                                   float* __restrict__ H) {
    const int tid = threadIdx.x;
    const int wid = tid >> 6, lane = tid & 63;
    const int lane15 = lane & 15, kg = (lane >> 4) * 8;
    const int brow = blockIdx.x * 64;
    const int grow = brow + wid * 16 + lane15;
    const float* xr = X + (size_t)(grow < NN ? grow : 0) * IND + kg;

    v4f acc[8];
#pragma unroll
    for (int i = 0; i < 8; i++) acc[i] = (v4f)0.f;

    float4 x0 = *reinterpret_cast<const float4*>(xr);
    float4 x1 = *reinterpret_cast<const float4*>(xr + 4);
    float4 x2 = *reinterpret_cast<const float4*>(xr + 32);
    float4 x3 = *reinterpret_cast<const float4*>(xr + 36);

#pragma unroll
    for (int it = 0; it < 8; ++it) {  // K chunks of 64
        float4 n0, n1, n2, n3;
        if (it < 7) {
            const float* xn = xr + (it + 1) * 64;
            n0 = *reinterpret_cast<const float4*>(xn);
            n1 = *reinterpret_cast<const float4*>(xn + 4);
            n2 = *reinterpret_cast<const float4*>(xn + 32);
            n3 = *reinterpret_cast<const float4*>(xn + 36);
        }
        v8s ah0, al0, ah1, al1;
        split8(x0, x1, ah0, al0);
        split8(x2, x3, ah1, al1);
        const ushort* bhb = Wh + it * 64 + kg;
        const ushort* blb = Wl + it * 64 + kg;
#pragma unroll
        for (int nf = 0; nf < 8; nf++) {
            const ushort* bp = bhb + (size_t)(nf * 16 + lane15) * IND;
            const ushort* bq = blb + (size_t)(nf * 16 + lane15) * IND;
            v8s bh0 = *reinterpret_cast<const v8s*>(bp);
            v8s bh1 = *reinterpret_cast<const v8s*>(bp + 32);
            v8s bl0 = *reinterpret_cast<const v8s*>(bq);
            v8s bl1 = *reinterpret_cast<const v8s*>(bq + 32);
            v4f a = acc[nf];
            a = __builtin_amdgcn_mfma_f32_16x16x32_bf16(ah0, bh0, a, 0, 0, 0);
            a = __builtin_amdgcn_mfma_f32_16x16x32_bf16(al0, bh0, a, 0, 0, 0);
            a = __builtin_amdgcn_mfma_f32_16x16x32_bf16(ah0, bl0, a, 0, 0, 0);
            a = __builtin_amdgcn_mfma_f32_16x16x32_bf16(ah1, bh1, a, 0, 0, 0);
            a = __builtin_amdgcn_mfma_f32_16x16x32_bf16(al1, bh1, a, 0, 0, 0);
            a = __builtin_amdgcn_mfma_f32_16x16x32_bf16(ah1, bl1, a, 0, 0, 0);
            acc[nf] = a;
        }
        x0 = n0; x1 = n1; x2 = n2; x3 = n3;
    }
#pragma unroll
    for (int nf = 0; nf < 8; nf++) {
        int col = nf * 16 + lane15;
        float bias = B[col];
#pragma unroll
        for (int r = 0; r < 4; r++) {
            int g = brow + wid * 16 + (lane >> 4) * 4 + r;
            if (g < NN) H[(size_t)g * HID + col] = acc[nf][r] + bias;
        }
    }
}

// ---------------- Aggregation: z = h + sum w*h[src] (CSR, float4, 2-way unroll) ----------------

__global__ __launch_bounds__(256) void agg_kernel(const float* __restrict__ h,
                                                  const int* __restrict__ rp,
                                                  const int* __restrict__ cs,
                                                  const float* __restrict__ cw,
                                                  float* __restrict__ z) {
    const int node = blockIdx.x * 8 + (threadIdx.x >> 5);
    const int c4 = (threadIdx.x & 31) << 2;
    const float* hp = h + c4;
    v4f acc0 = *reinterpret_cast<const v4f*>(hp + (size_t)node * HID);
    v4f acc1 = (v4f)0.f;
    int k = rp[node];
    const int ke = rp[node + 1];
    for (; k + 1 < ke; k += 2) {
        int s0 = cs[k], s1 = cs[k + 1];
        float w0 = cw[k], w1 = cw[k + 1];
        v4f v0 = *reinterpret_cast<const v4f*>(hp + (size_t)s0 * HID);
        v4f v1 = *reinterpret_cast<const v4f*>(hp + (size_t)s1 * HID);
        acc0 = acc0 + w0 * v0;
        acc1 = acc1 + w1 * v1;
    }
    if (k < ke) {
        acc0 = acc0 + cw[k] * *reinterpret_cast<const v4f*>(hp + (size_t)cs[k] * HID);
    }
    *reinterpret_cast<v4f*>(z + (size_t)node * HID + c4) = acc0 + acc1;
}

// ---------------- Fused MLP (split-bf16 MFMA): h = relu(relu(z@W1+b1)@W2+b2) ----------------
// 256 thr = 4 waves; BM=64; direct-register z loads; per-wave LDS transpose
// slice (no barriers). LAST=1 additionally fuses the readout GEMM.

template <int LAST>
__global__ __launch_bounds__(256, 2) void mlp_mfma(const float* __restrict__ Z,
                                                   const ushort* __restrict__ W1h, const ushort* __restrict__ W1l,
                                                   const float* __restrict__ B1,
                                                   const ushort* __restrict__ W2h, const ushort* __restrict__ W2l,
                                                   const float* __restrict__ B2,
                                                   const ushort* __restrict__ RWh, const ushort* __restrict__ RWl,
                                                   const float* __restrict__ RB,
                                                   float* __restrict__ H, float* __restrict__ OUT) {
    __shared__ __align__(16) ushort Ah[64 * 128];
    __shared__ __align__(16) ushort Al[64 * 128];
    const int tid = threadIdx.x;
    const int wid = tid >> 6, lane = tid & 63;
    const int lane15 = lane & 15, kg = (lane >> 4) * 8;
    const int brow = blockIdx.x * 64;
    const int grow = brow + wid * 16 + lane15;
    const int rowl = wid * 16 + lane15;
    const int sw = (rowl & 7) << 3;

    // A fragments for GEMM1 directly from global z
    const float* zr = Z + (size_t)(grow < NN ? grow : 0) * HID + kg;
    v8s ah[4], al[4];
#pragma unroll
    for (int ks = 0; ks < 4; ks++) {
        float4 a0 = *reinterpret_cast<const float4*>(zr + ks * 32);
        float4 a1 = *reinterpret_cast<const float4*>(zr + ks * 32 + 4);
        split8(a0, a1, ah[ks], al[ks]);
    }

    v4f acc[8];
#pragma unroll
    for (int i = 0; i < 8; i++) acc[i] = (v4f)0.f;

    // GEMM1: hidden = z @ W1
#pragma unroll
    for (int nf = 0; nf < 8; nf++) {
        const ushort* bp = W1h + (size_t)(nf * 16 + lane15) * HID + kg;
        const ushort* bq = W1l + (size_t)(nf * 16 + lane15) * HID + kg;
        v4f a = acc[nf];
#pragma unroll
        for (int ks = 0; ks < 4; ks++) {
            v8s bh = *reinterpret_cast<const v8s*>(bp + ks * 32);
            v8s bl = *reinterpret_cast<const v8s*>(bq + ks * 32);
            a = __builtin_amdgcn_mfma_f32_16x16x32_bf16(ah[ks], bh, a, 0, 0, 0);
            a = __builtin_amdgcn_mfma_f32_16x16x32_bf16(al[ks], bh, a, 0, 0, 0);
            a = __builtin_amdgcn_mfma_f32_16x16x32_bf16(ah[ks], bl, a, 0, 0, 0);
        }
        acc[nf] = a;
    }
    // bias + relu -> own LDS slice (hidden[row][k=col]), then reload A frags
#pragma unroll
    for (int nf = 0; nf < 8; nf++) {
        int col = nf * 16 + lane15;
        float b = B1[col];
#pragma unroll
        for (int r = 0; r < 4; r++) {
            int rl2 = wid * 16 + (lane >> 4) * 4 + r;
            float v = acc[nf][r] + b;
            v = v > 0.f ? v : 0.f;
            ushort h = f2bf(v);
            int idx = rl2 * 128 + (col ^ ((rl2 & 7) << 3));
            Ah[idx] = h;
            Al[idx] = f2bf(v - bf2f(h));
        }
        acc[nf] = (v4f)0.f;
    }
#pragma unroll
    for (int ks = 0; ks < 4; ks++) {
        int idx = rowl * 128 + ((ks * 32 + kg) ^ sw);
        ah[ks] = *reinterpret_cast<const v8s*>(&Ah[idx]);
        al[ks] = *reinterpret_cast<const v8s*>(&Al[idx]);
    }
    // GEMM2: out = hidden @ W2
#pragma unroll
    for (int nf = 0; nf < 8; nf++) {
        const ushort* bp = W2h + (size_t)(nf * 16 + lane15) * HID + kg;
        const ushort* bq = W2l + (size_t)(nf * 16 + lane15) * HID + kg;
        v4f a = acc[nf];
#pragma unroll
        for (int ks = 0; ks < 4; ks++) {
            v8s bh = *reinterpret_cast<const v8s*>(bp + ks * 32);
            v8s bl = *reinterpret_cast<const v8s*>(bq + ks * 32);
            a = __builtin_amdgcn_mfma_f32_16x16x32_bf16(ah[ks], bh, a, 0, 0, 0);
            a = __builtin_amdgcn_mfma_f32_16x16x32_bf16(al[ks], bh, a, 0, 0, 0);
            a = __builtin_amdgcn_mfma_f32_16x16x32_bf16(ah[ks], bl, a, 0, 0, 0);
        }
        acc[nf] = a;
    }

    if (LAST == 0) {
#pragma unroll
        for (int nf = 0; nf < 8; nf++) {
            int col = nf * 16 + lane15;
            float b = B2[col];
#pragma unroll
            for (int r = 0; r < 4; r++) {
                int g = brow + wid * 16 + (lane >> 4) * 4 + r;
                if (g < NN) H[(size_t)g * HID + col] = fmaxf(acc[nf][r] + b, 0.f);
            }
        }
    } else {
        // h3 = relu(acc+b2) -> LDS, reload as A frags, readout GEMM
#pragma unroll
        for (int nf = 0; nf < 8; nf++) {
            int col = nf * 16 + lane15;
            float b = B2[col];
#pragma unroll
            for (int r = 0; r < 4; r++) {
                int rl2 = wid * 16 + (lane >> 4) * 4 + r;
                float v = fmaxf(acc[nf][r] + b, 0.f);
                ushort h = f2bf(v);
                int idx = rl2 * 128 + (col ^ ((rl2 & 7) << 3));
                Ah[idx] = h;
                Al[idx] = f2bf(v - bf2f(h));
            }
        }
#pragma unroll
        for (int ks = 0; ks < 4; ks++) {
            int idx = rowl * 128 + ((ks * 32 + kg) ^ sw);
            ah[ks] = *reinterpret_cast<const v8s*>(&Ah[idx]);
            al[ks] = *reinterpret_cast<const v8s*>(&Al[idx]);
        }
        v4f acc3[3];
#pragma unroll
        for (int i = 0; i < 3; i++) acc3[i] = (v4f)0.f;
#pragma unroll
        for (int nf = 0; nf < 3; nf++) {
            const ushort* bp = RWh + (size_t)(nf * 16 + lane15) * HID + kg;
            const ushort* bq = RWl + (size_t)(nf * 16 + lane15) * HID + kg;
            v4f a = acc3[nf];
#pragma unroll
            for (int ks = 0; ks < 4; ks++) {
                v8s bh = *reinterpret_cast<const v8s*>(bp + ks * 32);
                v8s bl = *reinterpret_cast<const v8s*>(bq + ks * 32);
                a = __builtin_amdgcn_mfma_f32_16x16x32_bf16(ah[ks], bh, a, 0, 0, 0);
                a = __builtin_amdgcn_mfma_f32_16x16x32_bf16(al[ks], bh, a, 0, 0, 0);
                a = __builtin_amdgcn_mfma_f32_16x16x32_bf16(ah[ks], bl, a, 0, 0, 0);
            }
            acc3[nf] = a;
        }
#pragma unroll
        for (int nf = 0; nf < 3; nf++) {
            int col = nf * 16 + lane15;
            if (col < OUTD) {
                float b = RB[col];
#pragma unroll
                for (int r = 0; r < 4; r++) {
                    int g = brow + wid * 16 + (lane >> 4) * 4 + r;
                    if (g < NN) OUT[(size_t)g * OUTD + col] = acc3[nf][r] + b;
                }
            }
        }
    }
}

// ---------------- launch ----------------

extern "C" void kernel_launch(void* const* d_in, const int* in_sizes, int n_in,
                              void* d_out, int out_size, void* d_ws, size_t ws_size,
                              hipStream_t stream) {
    const float* features = (const float*)d_in[0];
    const int* src = (const int*)d_in[1];
    const int* dst = (const int*)d_in[2];
    const float* ew = (const float*)d_in[3];
    const float* embW = (const float*)d_in[4];
    const float* embB = (const float*)d_in[5];
    const float* W1 = (const float*)d_in[6];
    const float* B1 = (const float*)d_in[7];
    const float* W2 = (const float*)d_in[8];
    const float* B2 = (const float*)d_in[9];
    const float* roW = (const float*)d_in[10];
    const float* roB = (const float*)d_in[11];
    float* out = (float*)d_out;

    float* h = (float*)d_ws;                           // NN*HID
    float* z = h + (size_t)NN * HID;                   // NN*HID
    int* rp = (int*)(z + (size_t)NN * HID);            // NN+16
    int* cursor = rp + NN + 16;                        // NN
    int* deg = cursor + NN;                            // NN
    int* csr_src = deg + NN;                           // NE
    float* csr_w = (float*)(csr_src + NE);             // NE
    ushort* embWt_h = (ushort*)(csr_w + NE);           // IND*HID
    ushort* embWt_l = embWt_h + (size_t)IND * HID;
    ushort* W1t_h = embWt_l + (size_t)IND * HID;       // NL*HID*HID each
    ushort* W1t_l = W1t_h + (size_t)NL * HID * HID;
    ushort* W2t_h = W1t_l + (size_t)NL * HID * HID;
    ushort* W2t_l = W2t_h + (size_t)NL * HID * HID;
    ushort* roWt_h = W2t_l + (size_t)NL * HID * HID;   // 48*128 each
    ushort* roWt_l = roWt_h + 48 * 128;

    conv_emb<<<64, 256, 0, stream>>>(embW, embWt_h, embWt_l);
    conv_mlp<<<96, 256, 0, stream>>>(W1, W2, W1t_h, W1t_l, W2t_h, W2t_l);
    conv_ro<<<24, 256, 0, stream>>>(roW, roWt_h, roWt_l);

    hipMemsetAsync(deg, 0, NN * sizeof(int), stream);
    count_kernel<<<(NE + 255) / 256, 256, 0, stream>>>(dst, deg);
    scan_kernel<<<1, 1024, 0, stream>>>(deg, rp, cursor);
    fill_kernel<<<(NE + 255) / 256, 256, 0, stream>>>(src, dst, ew, cursor, csr_src, csr_w);

    emb_mfma<<<(NN + 63) / 64, 256, 0, stream>>>(features, embWt_h, embWt_l, embB, h);

    for (int l = 0; l < NL; l++) {
        agg_kernel<<<NN / 8, 256, 0, stream>>>(h, rp, csr_src, csr_w, z);
        const ushort* w1h = W1t_h + (size_t)l * HID * HID;
        const ushort* w1l = W1t_l + (size_t)l * HID * HID;
        const ushort* w2h = W2t_h + (size_t)l * HID * HID;
        const ushort* w2l = W2t_l + (size_t)l * HID * HID;
        const float* b1 = B1 + (size_t)l * HID;
        const float* b2 = B2 + (size_t)l * HID;
        if (l < NL - 1) {
            mlp_mfma<0><<<(NN + 63) / 64, 256, 0, stream>>>(
                z, w1h, w1l, b1, w2h, w2l, b2, roWt_h, roWt_l, roB, h, out);
        } else {
            mlp_mfma<1><<<(NN + 63) / 64, 256, 0, stream>>>(
                z, w1h, w1l, b1, w2h, w2l, b2, roWt_h, roWt_l, roB, h, out);
        }
    }
}

// Round 5
// 640.662 us; speedup vs baseline: 1.6388x; 1.2777x over previous
//
#include <hip/hip_runtime.h>

#define NN 50000
#define NE 625000
#define IND 512
#define HID 128
#define OUTD 40
#define NL 3

typedef short v8s __attribute__((ext_vector_type(8)));
typedef float v4f __attribute__((ext_vector_type(4)));
typedef const __attribute__((address_space(1))) unsigned int gu32;
typedef __attribute__((address_space(3))) unsigned int lu32;

#define MFMA __builtin_amdgcn_mfma_f32_16x16x32_bf16

__device__ inline ushort f2bf(float x) {
    unsigned u = __float_as_uint(x);
    u += 0x7FFF + ((u >> 16) & 1);  // RNE
    return (ushort)(u >> 16);
}
__device__ inline float bf2f(ushort b) { return __uint_as_float(((unsigned)b) << 16); }

__device__ inline void split8(float4 a, float4 b, v8s& hi, v8s& lo) {
    float v[8] = {a.x, a.y, a.z, a.w, b.x, b.y, b.z, b.w};
    v8s h, l;
#pragma unroll
    for (int i = 0; i < 8; i++) {
        ushort hu = f2bf(v[i]);
        h[i] = (short)hu;
        l[i] = (short)f2bf(v[i] - bf2f(hu));
    }
    hi = h;
    lo = l;
}

// async stage NI*4KB from global (linear) into LDS (linear), 16B/lane
template <int NI>
__device__ inline void stage(const ushort* __restrict__ g, ushort* l, int tid) {
    const int wid = tid >> 6;
#pragma unroll
    for (int j = 0; j < NI; j++) {
        __builtin_amdgcn_global_load_lds(
            (gu32*)((const char*)g + (size_t)(j * 256 + tid) * 16),
            (lu32*)((char*)l + (j * 256 + (wid << 6)) * 16), 16, 0, 0);
    }
}

// ---------------- CSR build ----------------

__global__ __launch_bounds__(256) void count_kernel(const int* __restrict__ dst,
                                                    int* __restrict__ deg) {
    int e = blockIdx.x * 256 + threadIdx.x;
    if (e < NE) atomicAdd(&deg[dst[e]], 1);
}

__global__ __launch_bounds__(1024) void scan_kernel(const int* __restrict__ deg,
                                                    int* __restrict__ rp,
                                                    int* __restrict__ cursor) {
    __shared__ int sums[1024];
    const int CH = (NN + 1023) / 1024;  // 49
    int t = threadIdx.x;
    int beg = t * CH;
    int end = beg + CH < NN ? beg + CH : NN;
    int s = 0;
    for (int i = beg; i < end; i++) s += deg[i];
    sums[t] = s;
    __syncthreads();
    for (int off = 1; off < 1024; off <<= 1) {
        int v = (t >= off) ? sums[t - off] : 0;
        __syncthreads();
        sums[t] += v;
        __syncthreads();
    }
    int run = sums[t] - s;  // exclusive prefix
    for (int i = beg; i < end; i++) {
        rp[i] = run;
        cursor[i] = run;
        run += deg[i];
    }
    if (t == 1023) rp[NN] = run;
}

__global__ __launch_bounds__(256) void fill_kernel(const int* __restrict__ src,
                                                   const int* __restrict__ dst,
                                                   const float* __restrict__ ew,
                                                   int* __restrict__ cursor,
                                                   int2* __restrict__ csr) {
    int e = blockIdx.x * 256 + threadIdx.x;
    if (e < NE) {
        int d = dst[e];
        int pos = atomicAdd(&cursor[d], 1);
        csr[pos] = make_int2(src[e], __float_as_int(ew[e]));
    }
}

// ---------------- weight packers: transpose + hi/lo split + baked XOR swizzle ----------------
// emb: P[it=k/64][plane][col][kl^((col&7)<<3)]  (chunk = 16384 ushorts = 32KB)

__global__ __launch_bounds__(256) void conv_emb(const float* __restrict__ W,
                                                ushort* __restrict__ P) {
    int idx = blockIdx.x * 256 + threadIdx.x;  // 512k x 128c
    int k = idx >> 7;
    int c = idx & 127;
    float v = W[(size_t)k * HID + c];
    ushort hb = f2bf(v);
    ushort lb = f2bf(v - bf2f(hb));
    int it = k >> 6, kl = k & 63;
    int pos = it * 16384 + c * 64 + (kl ^ ((c & 7) << 3));
    P[pos] = hb;
    P[pos + 8192] = lb;
}

// mlp: P[l][g][q=c/32][plane][cl][k^((c&7)<<3)]  (chunk = 8192 ushorts = 16KB)
__global__ __launch_bounds__(256) void conv_mlp(const float* __restrict__ W1,
                                                const float* __restrict__ W2,
                                                ushort* __restrict__ P) {
    int idx = blockIdx.x * 256 + threadIdx.x;  // 6 * 128k * 128c
    int lg = idx >> 14;
    int r = idx & 16383;
    int k = r >> 7, c = r & 127;
    int l = lg >> 1, g = lg & 1;
    const float* src = (g ? W2 : W1) + (size_t)l * HID * HID;
    float v = src[(size_t)k * HID + c];
    ushort hb = f2bf(v);
    ushort lb = f2bf(v - bf2f(hb));
    int q = c >> 5, cl = c & 31;
    int pos = lg * 32768 + q * 8192 + cl * 128 + (k ^ ((c & 7) << 3));
    P[pos] = hb;
    P[pos + 4096] = lb;
}

// readout W [128][40] f32 -> padded transposed [48][128] bf16 hi/lo
__global__ __launch_bounds__(256) void conv_ro(const float* __restrict__ W,
                                               ushort* __restrict__ Th,
                                               ushort* __restrict__ Tl) {
    int idx = blockIdx.x * 256 + threadIdx.x;  // 48*128 = 6144
    int c = idx >> 7;
    int kk = idx & 127;
    float v = (c < OUTD) ? W[(size_t)kk * OUTD + c] : 0.f;
    ushort h = f2bf(v);
    Th[idx] = h;
    Tl[idx] = f2bf(v - bf2f(h));
}

// ---------------- Embedding GEMM: [NN,512]@[512,128]+b ----------------
// 256 thr / BM=64. W chunks (32KB) async-staged into 2-deep LDS ring with
// counted vmcnt; X per-lane register loads prefetched 1 chunk ahead.

__global__ __launch_bounds__(256) void emb_mfma(const float* __restrict__ X,
                                                const ushort* __restrict__ Wp,
                                                const float* __restrict__ B,
                                                float* __restrict__ H) {
    __shared__ __align__(16) ushort Wb[2][16384];
    const int tid = threadIdx.x;
    const int wid = tid >> 6, lane = tid & 63;
    const int lane15 = lane & 15, kg = (lane >> 4) * 8;
    const int swc = (lane15 & 7) << 3;
    const int brow = blockIdx.x * 64;
    const int grow = brow + wid * 16 + lane15;
    const float* xr = X + (size_t)(grow < NN ? grow : 0) * IND + kg;

    v4f acc[8];
#pragma unroll
    for (int i = 0; i < 8; i++) acc[i] = (v4f)0.f;

    float4 x0 = *reinterpret_cast<const float4*>(xr);
    float4 x1 = *reinterpret_cast<const float4*>(xr + 4);
    float4 x2 = *reinterpret_cast<const float4*>(xr + 32);
    float4 x3 = *reinterpret_cast<const float4*>(xr + 36);
    stage<8>(Wp, &Wb[0][0], tid);

    for (int it = 0; it < 8; ++it) {
        float4 n0, n1, n2, n3;
        if (it < 7) {
            const float* xn = xr + (it + 1) * 64;
            n0 = *reinterpret_cast<const float4*>(xn);
            n1 = *reinterpret_cast<const float4*>(xn + 4);
            n2 = *reinterpret_cast<const float4*>(xn + 32);
            n3 = *reinterpret_cast<const float4*>(xn + 36);
            stage<8>(Wp + (size_t)(it + 1) * 16384, &Wb[(it + 1) & 1][0], tid);
            asm volatile("s_waitcnt vmcnt(12)" ::: "memory");  // prior X + stage done
        } else {
            asm volatile("s_waitcnt vmcnt(0)" ::: "memory");
        }
        __builtin_amdgcn_s_barrier();  // buf[it&1] staged by all waves
        v8s ah0, al0, ah1, al1;
        split8(x0, x1, ah0, al0);
        split8(x2, x3, ah1, al1);
        const ushort* cb = &Wb[it & 1][0];
        const int s0 = kg ^ swc;
        const int s1 = (32 + kg) ^ swc;
        __builtin_amdgcn_s_setprio(1);
#pragma unroll
        for (int nf = 0; nf < 8; nf++) {
            int rb = (nf * 16 + lane15) * 64;
            v8s bh0 = *reinterpret_cast<const v8s*>(&cb[rb + s0]);
            v8s bl0 = *reinterpret_cast<const v8s*>(&cb[8192 + rb + s0]);
            v8s bh1 = *reinterpret_cast<const v8s*>(&cb[rb + s1]);
            v8s bl1 = *reinterpret_cast<const v8s*>(&cb[8192 + rb + s1]);
            v4f a = acc[nf];
            a = MFMA(ah0, bh0, a, 0, 0, 0);
            a = MFMA(al0, bh0, a, 0, 0, 0);
            a = MFMA(ah0, bl0, a, 0, 0, 0);
            a = MFMA(ah1, bh1, a, 0, 0, 0);
            a = MFMA(al1, bh1, a, 0, 0, 0);
            a = MFMA(ah1, bl1, a, 0, 0, 0);
            acc[nf] = a;
        }
        __builtin_amdgcn_s_setprio(0);
        asm volatile("s_waitcnt lgkmcnt(0)" ::: "memory");  // ds_reads complete
        __builtin_amdgcn_s_barrier();                        // before ring overwrite
        x0 = n0; x1 = n1; x2 = n2; x3 = n3;
    }
#pragma unroll
    for (int nf = 0; nf < 8; nf++) {
        int col = nf * 16 + lane15;
        float bias = B[col];
#pragma unroll
        for (int r = 0; r < 4; r++) {
            int g = brow + wid * 16 + (lane >> 4) * 4 + r;
            if (g < NN) H[(size_t)g * HID + col] = acc[nf][r] + bias;
        }
    }
}

// ---------------- Aggregation: z = h + sum w*h[src] (CSR, 4-way unroll) ----------------

__global__ __launch_bounds__(256) void agg_kernel(const float* __restrict__ h,
                                                  const int* __restrict__ rp,
                                                  const int2* __restrict__ csr,
                                                  float* __restrict__ z) {
    const int node = blockIdx.x * 8 + (threadIdx.x >> 5);
    const int c4 = (threadIdx.x & 31) << 2;
    const float* hp = h + c4;
    v4f a0 = *reinterpret_cast<const v4f*>(hp + (size_t)node * HID);
    v4f a1 = (v4f)0.f, a2 = (v4f)0.f, a3 = (v4f)0.f;
    int k = rp[node];
    const int ke = rp[node + 1];
    for (; k + 3 < ke; k += 4) {
        int2 e0 = csr[k], e1 = csr[k + 1], e2 = csr[k + 2], e3 = csr[k + 3];
        a0 += __int_as_float(e0.y) * *reinterpret_cast<const v4f*>(hp + (size_t)e0.x * HID);
        a1 += __int_as_float(e1.y) * *reinterpret_cast<const v4f*>(hp + (size_t)e1.x * HID);
        a2 += __int_as_float(e2.y) * *reinterpret_cast<const v4f*>(hp + (size_t)e2.x * HID);
        a3 += __int_as_float(e3.y) * *reinterpret_cast<const v4f*>(hp + (size_t)e3.x * HID);
    }
    for (; k < ke; k++) {
        int2 e = csr[k];
        a0 += __int_as_float(e.y) * *reinterpret_cast<const v4f*>(hp + (size_t)e.x * HID);
    }
    *reinterpret_cast<v4f*>(z + (size_t)node * HID + c4) = (a0 + a1) + (a2 + a3);
}

// ---------------- Fused MLP: h = relu(relu(z@W1+b1)@W2+b2) [+ readout] ----------------
// 256 thr / BM=64. 8 W chunks (16KB each) through 2-deep LDS ring, counted
// vmcnt; hidden transposed via per-wave LDS slice (no extra barriers).

template <int LAST>
__global__ __launch_bounds__(256) void mlp_mfma(const float* __restrict__ Z,
                                                const ushort* __restrict__ Wlp,
                                                const float* __restrict__ B1,
                                                const float* __restrict__ B2,
                                                const ushort* __restrict__ RWh,
                                                const ushort* __restrict__ RWl,
                                                const float* __restrict__ RB,
                                                float* __restrict__ H,
                                                float* __restrict__ OUT) {
    __shared__ __align__(16) ushort Wb[2][8192];
    __shared__ __align__(16) ushort Hh[64 * 128];
    __shared__ __align__(16) ushort Hl[64 * 128];
    const int tid = threadIdx.x;
    const int wid = tid >> 6, lane = tid & 63;
    const int lane15 = lane & 15, kg = (lane >> 4) * 8;
    const int swc = (lane15 & 7) << 3;
    const int brow = blockIdx.x * 64;
    const int grow = brow + wid * 16 + lane15;
    const int rowl = wid * 16 + lane15;
    const int sw = (rowl & 7) << 3;

    const float* zr = Z + (size_t)(grow < NN ? grow : 0) * HID + kg;
    float4 za[4], zb[4];
#pragma unroll
    for (int ks = 0; ks < 4; ks++) {
        za[ks] = *reinterpret_cast<const float4*>(zr + ks * 32);
        zb[ks] = *reinterpret_cast<const float4*>(zr + ks * 32 + 4);
    }
    stage<4>(Wlp, &Wb[0][0], tid);

    v8s ah[4], al[4];
    v4f acc[8];
#pragma unroll
    for (int i = 0; i < 8; i++) acc[i] = (v4f)0.f;

    for (int q = 0; q < 8; q++) {
        if (q < 7) {
            stage<4>(Wlp + (size_t)(q + 1) * 8192, &Wb[(q + 1) & 1][0], tid);
            asm volatile("s_waitcnt vmcnt(4)" ::: "memory");
        } else {
            asm volatile("s_waitcnt vmcnt(0)" ::: "memory");
        }
        __builtin_amdgcn_s_barrier();
        if (q == 0) {
#pragma unroll
            for (int ks = 0; ks < 4; ks++) split8(za[ks], zb[ks], ah[ks], al[ks]);
        }
        if (q == 4) {  // reload A-frags from hidden (own wave slice)
#pragma unroll
            for (int ks = 0; ks < 4; ks++) {
                int idx = rowl * 128 + ((ks * 32 + kg) ^ sw);
                ah[ks] = *reinterpret_cast<const v8s*>(&Hh[idx]);
                al[ks] = *reinterpret_cast<const v8s*>(&Hl[idx]);
            }
        }
        const ushort* cb = &Wb[q & 1][0];
        const int nfb = (q & 3) * 2;
        __builtin_amdgcn_s_setprio(1);
#pragma unroll
        for (int t = 0; t < 2; t++) {
            int rb = (t * 16 + lane15) * 128;
            v4f a = acc[nfb + t];
#pragma unroll
            for (int ks = 0; ks < 4; ks++) {
                int s = (ks * 32 + kg) ^ swc;
                v8s bh = *reinterpret_cast<const v8s*>(&cb[rb + s]);
                v8s bl = *reinterpret_cast<const v8s*>(&cb[4096 + rb + s]);
                a = MFMA(ah[ks], bh, a, 0, 0, 0);
                a = MFMA(al[ks], bh, a, 0, 0, 0);
                a = MFMA(ah[ks], bl, a, 0, 0, 0);
            }
            acc[nfb + t] = a;
        }
        __builtin_amdgcn_s_setprio(0);
        if (q < 4) {  // GEMM1 chunk done: bias+relu -> hidden LDS slice
#pragma unroll
            for (int t = 0; t < 2; t++) {
                int nf = nfb + t;
                int col = nf * 16 + lane15;
                float b = B1[col];
#pragma unroll
                for (int r = 0; r < 4; r++) {
                    int rl2 = wid * 16 + (lane >> 4) * 4 + r;
                    float v = acc[nf][r] + b;
                    v = v > 0.f ? v : 0.f;
                    ushort hb = f2bf(v);
                    int idx = rl2 * 128 + (col ^ ((rl2 & 7) << 3));
                    Hh[idx] = hb;
                    Hl[idx] = f2bf(v - bf2f(hb));
                }
                acc[nf] = (v4f)0.f;
            }
        } else if (LAST == 0) {
#pragma unroll
            for (int t = 0; t < 2; t++) {
                int nf = nfb + t;
                int col = nf * 16 + lane15;
                float b = B2[col];
#pragma unroll
                for (int r = 0; r < 4; r++) {
                    int g = brow + wid * 16 + (lane >> 4) * 4 + r;
                    if (g < NN) H[(size_t)g * HID + col] = fmaxf(acc[nf][r] + b, 0.f);
                }
            }
        } else {  // LAST: h3 -> hidden LDS slice for readout
#pragma unroll
            for (int t = 0; t < 2; t++) {
                int nf = nfb + t;
                int col = nf * 16 + lane15;
                float b = B2[col];
#pragma unroll
                for (int r = 0; r < 4; r++) {
                    int rl2 = wid * 16 + (lane >> 4) * 4 + r;
                    float v = fmaxf(acc[nf][r] + b, 0.f);
                    ushort hb = f2bf(v);
                    int idx = rl2 * 128 + (col ^ ((rl2 & 7) << 3));
                    Hh[idx] = hb;
                    Hl[idx] = f2bf(v - bf2f(hb));
                }
            }
        }
        asm volatile("s_waitcnt lgkmcnt(0)" ::: "memory");
        __builtin_amdgcn_s_barrier();
    }

    if (LAST) {
#pragma unroll
        for (int ks = 0; ks < 4; ks++) {
            int idx = rowl * 128 + ((ks * 32 + kg) ^ sw);
            ah[ks] = *reinterpret_cast<const v8s*>(&Hh[idx]);
            al[ks] = *reinterpret_cast<const v8s*>(&Hl[idx]);
        }
        v4f a3[3];
#pragma unroll
        for (int i = 0; i < 3; i++) a3[i] = (v4f)0.f;
#pragma unroll
        for (int nf = 0; nf < 3; nf++) {
            const ushort* bp = RWh + (size_t)(nf * 16 + lane15) * HID + kg;
            const ushort* bq = RWl + (size_t)(nf * 16 + lane15) * HID + kg;
            v4f a = a3[nf];
#pragma unroll
            for (int ks = 0; ks < 4; ks++) {
                v8s bh = *reinterpret_cast<const v8s*>(bp + ks * 32);
                v8s bl = *reinterpret_cast<const v8s*>(bq + ks * 32);
                a = MFMA(ah[ks], bh, a, 0, 0, 0);
                a = MFMA(al[ks], bh, a, 0, 0, 0);
                a = MFMA(ah[ks], bl, a, 0, 0, 0);
            }
            a3[nf] = a;
        }
#pragma unroll
        for (int nf = 0; nf < 3; nf++) {
            int col = nf * 16 + lane15;
            if (col < OUTD) {
                float b = RB[col];
#pragma unroll
                for (int r = 0; r < 4; r++) {
                    int g = brow + wid * 16 + (lane >> 4) * 4 + r;
                    if (g < NN) OUT[(size_t)g * OUTD + col] = a3[nf][r] + b;
                }
            }
        }
    }
}

// ---------------- launch ----------------

extern "C" void kernel_launch(void* const* d_in, const int* in_sizes, int n_in,
                              void* d_out, int out_size, void* d_ws, size_t ws_size,
                              hipStream_t stream) {
    const float* features = (const float*)d_in[0];
    const int* src = (const int*)d_in[1];
    const int* dst = (const int*)d_in[2];
    const float* ew = (const float*)d_in[3];
    const float* embW = (const float*)d_in[4];
    const float* embB = (const float*)d_in[5];
    const float* W1 = (const float*)d_in[6];
    const float* B1 = (const float*)d_in[7];
    const float* W2 = (const float*)d_in[8];
    const float* B2 = (const float*)d_in[9];
    const float* roW = (const float*)d_in[10];
    const float* roB = (const float*)d_in[11];
    float* out = (float*)d_out;

    float* h = (float*)d_ws;                          // NN*HID f32
    float* z = h + (size_t)NN * HID;                  // NN*HID f32
    int* rp = (int*)(z + (size_t)NN * HID);           // NN+16
    int2* csr = (int2*)(rp + NN + 16);                // NE int2
    int* cursor = (int*)(csr + NE);                   // NN
    int* deg = cursor + NN;                           // NN
    ushort* Wemb_p = (ushort*)(deg + NN);             // 8*16384
    ushort* Wmlp_p = Wemb_p + 8 * 16384;              // NL*8*8192
    ushort* roWt_h = Wmlp_p + (size_t)NL * 8 * 8192;  // 48*128
    ushort* roWt_l = roWt_h + 48 * 128;

    conv_emb<<<256, 256, 0, stream>>>(embW, Wemb_p);
    conv_mlp<<<384, 256, 0, stream>>>(W1, W2, Wmlp_p);
    conv_ro<<<24, 256, 0, stream>>>(roW, roWt_h, roWt_l);

    hipMemsetAsync(deg, 0, NN * sizeof(int), stream);
    count_kernel<<<(NE + 255) / 256, 256, 0, stream>>>(dst, deg);
    scan_kernel<<<1, 1024, 0, stream>>>(deg, rp, cursor);
    fill_kernel<<<(NE + 255) / 256, 256, 0, stream>>>(src, dst, ew, cursor, csr);

    emb_mfma<<<(NN + 63) / 64, 256, 0, stream>>>(features, Wemb_p, embB, h);

    for (int l = 0; l < NL; l++) {
        agg_kernel<<<NN / 8, 256, 0, stream>>>(h, rp, csr, z);
        const ushort* wl = Wmlp_p + (size_t)l * 8 * 8192;
        const float* b1 = B1 + (size_t)l * HID;
        const float* b2 = B2 + (size_t)l * HID;
        if (l < NL - 1) {
            mlp_mfma<0><<<(NN + 63) / 64, 256, 0, stream>>>(
                z, wl, b1, b2, roWt_h, roWt_l, roB, h, out);
        } else {
            mlp_mfma<1><<<(NN + 63) / 64, 256, 0, stream>>>(
                z, wl, b1, b2, roWt_h, roWt_l, roB, h, out);
        }
    }
}

// Round 6
// 539.818 us; speedup vs baseline: 1.9450x; 1.1868x over previous
//
#include <hip/hip_runtime.h>

#define NN 50000
#define NE 625000
#define IND 512
#define HID 128
#define OUTD 40
#define NL 3
#define NB 196  // ceil(NN/256)

typedef short v8s __attribute__((ext_vector_type(8)));
typedef float v4f __attribute__((ext_vector_type(4)));
typedef const __attribute__((address_space(1))) unsigned int gu32;
typedef __attribute__((address_space(3))) unsigned int lu32;

#define MFMA __builtin_amdgcn_mfma_f32_16x16x32_bf16

__device__ inline ushort f2bf(float x) {
    unsigned u = __float_as_uint(x);
    u += 0x7FFF + ((u >> 16) & 1);  // RNE
    return (ushort)(u >> 16);
}
__device__ inline float bf2f(ushort b) { return __uint_as_float(((unsigned)b) << 16); }

__device__ inline void split8(float4 a, float4 b, v8s& hi, v8s& lo) {
    float v[8] = {a.x, a.y, a.z, a.w, b.x, b.y, b.z, b.w};
    v8s h, l;
#pragma unroll
    for (int i = 0; i < 8; i++) {
        ushort hu = f2bf(v[i]);
        h[i] = (short)hu;
        l[i] = (short)f2bf(v[i] - bf2f(hu));
    }
    hi = h;
    lo = l;
}

// async stage NI*4KB from global (linear) into LDS (linear), 16B/lane
template <int NI>
__device__ inline void stage(const ushort* __restrict__ g, ushort* l, int tid) {
    const int wid = tid >> 6;
#pragma unroll
    for (int j = 0; j < NI; j++) {
        __builtin_amdgcn_global_load_lds(
            (gu32*)((const char*)g + (size_t)(j * 256 + tid) * 16),
            (lu32*)((char*)l + (j * 256 + (wid << 6)) * 16), 16, 0, 0);
    }
}

// ---------------- CSR build ----------------

__global__ __launch_bounds__(256) void count_kernel(const int* __restrict__ dst,
                                                    int* __restrict__ deg) {
    int e = blockIdx.x * 256 + threadIdx.x;
    if (e < NE) atomicAdd(&deg[dst[e]], 1);
}

// hierarchical scan: (1) per-block exclusive prefix + block sum
__global__ __launch_bounds__(256) void scan1(const int* __restrict__ deg,
                                             int* __restrict__ ex,
                                             int* __restrict__ bsum) {
    __shared__ int s[256];
    int t = threadIdx.x;
    int idx = blockIdx.x * 256 + t;
    int d = idx < NN ? deg[idx] : 0;
    s[t] = d;
    __syncthreads();
#pragma unroll
    for (int off = 1; off < 256; off <<= 1) {
        int v = (t >= off) ? s[t - off] : 0;
        __syncthreads();
        s[t] += v;
        __syncthreads();
    }
    if (idx < NN) ex[idx] = s[t] - d;
    if (t == 255) bsum[blockIdx.x] = s[255];
}

// (2) scan the 196 block sums (single block)
__global__ __launch_bounds__(256) void scan2(const int* __restrict__ bsum,
                                             int* __restrict__ bpre) {
    __shared__ int s[256];
    int t = threadIdx.x;
    int d = t < NB ? bsum[t] : 0;
    s[t] = d;
    __syncthreads();
#pragma unroll
    for (int off = 1; off < 256; off <<= 1) {
        int v = (t >= off) ? s[t - off] : 0;
        __syncthreads();
        s[t] += v;
        __syncthreads();
    }
    if (t < NB) bpre[t] = s[t] - d;
}

// (3) rp/cursor = local prefix + block offset
__global__ __launch_bounds__(256) void scan3(const int* __restrict__ deg,
                                             const int* __restrict__ ex,
                                             const int* __restrict__ bpre,
                                             int* __restrict__ rp,
                                             int* __restrict__ cursor) {
    int idx = blockIdx.x * 256 + threadIdx.x;
    if (idx < NN) {
        int v = ex[idx] + bpre[blockIdx.x];
        rp[idx] = v;
        cursor[idx] = v;
        if (idx == NN - 1) rp[NN] = v + deg[idx];
    }
}

__global__ __launch_bounds__(256) void fill_kernel(const int* __restrict__ src,
                                                   const int* __restrict__ dst,
                                                   const float* __restrict__ ew,
                                                   int* __restrict__ cursor,
                                                   int2* __restrict__ csr) {
    int e = blockIdx.x * 256 + threadIdx.x;
    if (e < NE) {
        int d = dst[e];
        int pos = atomicAdd(&cursor[d], 1);
        csr[pos] = make_int2(src[e], __float_as_int(ew[e]));
    }
}

// ---------------- weight packers: transpose + hi/lo split + baked XOR swizzle ----------------
// emb: P[it=k/64][plane][col][kl^((col&7)<<3)]  (chunk = 16384 ushorts = 32KB)

__global__ __launch_bounds__(256) void conv_emb(const float* __restrict__ W,
                                                ushort* __restrict__ P) {
    int idx = blockIdx.x * 256 + threadIdx.x;  // 512k x 128c
    int k = idx >> 7;
    int c = idx & 127;
    float v = W[(size_t)k * HID + c];
    ushort hb = f2bf(v);
    ushort lb = f2bf(v - bf2f(hb));
    int it = k >> 6, kl = k & 63;
    int pos = it * 16384 + c * 64 + (kl ^ ((c & 7) << 3));
    P[pos] = hb;
    P[pos + 8192] = lb;
}

// mlp: P[l][g][q=c/32][plane][cl][k^((c&7)<<3)]  (chunk = 8192 ushorts = 16KB)
__global__ __launch_bounds__(256) void conv_mlp(const float* __restrict__ W1,
                                                const float* __restrict__ W2,
                                                ushort* __restrict__ P) {
    int idx = blockIdx.x * 256 + threadIdx.x;  // 6 * 128k * 128c
    int lg = idx >> 14;
    int r = idx & 16383;
    int k = r >> 7, c = r & 127;
    int l = lg >> 1, g = lg & 1;
    const float* src = (g ? W2 : W1) + (size_t)l * HID * HID;
    float v = src[(size_t)k * HID + c];
    ushort hb = f2bf(v);
    ushort lb = f2bf(v - bf2f(hb));
    int q = c >> 5, cl = c & 31;
    int pos = lg * 32768 + q * 8192 + cl * 128 + (k ^ ((c & 7) << 3));
    P[pos] = hb;
    P[pos + 4096] = lb;
}

// readout W [128][40] f32 -> padded transposed [48][128] bf16 hi/lo
__global__ __launch_bounds__(256) void conv_ro(const float* __restrict__ W,
                                               ushort* __restrict__ Th,
                                               ushort* __restrict__ Tl) {
    int idx = blockIdx.x * 256 + threadIdx.x;  // 48*128 = 6144
    int c = idx >> 7;
    int kk = idx & 127;
    float v = (c < OUTD) ? W[(size_t)kk * OUTD + c] : 0.f;
    ushort h = f2bf(v);
    Th[idx] = h;
    Tl[idx] = f2bf(v - bf2f(h));
}

// ---------------- Embedding GEMM: [NN,512]@[512,128]+b ----------------
// 256 thr / BM=64. W chunks (32KB) async-staged into 2-deep LDS ring with
// counted vmcnt; X per-lane register loads prefetched 1 chunk ahead.

__global__ __launch_bounds__(256) void emb_mfma(const float* __restrict__ X,
                                                const ushort* __restrict__ Wp,
                                                const float* __restrict__ B,
                                                float* __restrict__ H) {
    __shared__ __align__(16) ushort Wb[2][16384];
    const int tid = threadIdx.x;
    const int wid = tid >> 6, lane = tid & 63;
    const int lane15 = lane & 15, kg = (lane >> 4) * 8;
    const int swc = (lane15 & 7) << 3;
    const int brow = blockIdx.x * 64;
    const int grow = brow + wid * 16 + lane15;
    const float* xr = X + (size_t)(grow < NN ? grow : 0) * IND + kg;

    v4f acc[8];
#pragma unroll
    for (int i = 0; i < 8; i++) acc[i] = (v4f)0.f;

    float4 x0 = *reinterpret_cast<const float4*>(xr);
    float4 x1 = *reinterpret_cast<const float4*>(xr + 4);
    float4 x2 = *reinterpret_cast<const float4*>(xr + 32);
    float4 x3 = *reinterpret_cast<const float4*>(xr + 36);
    stage<8>(Wp, &Wb[0][0], tid);

    for (int it = 0; it < 8; ++it) {
        float4 n0, n1, n2, n3;
        if (it < 7) {
            const float* xn = xr + (it + 1) * 64;
            n0 = *reinterpret_cast<const float4*>(xn);
            n1 = *reinterpret_cast<const float4*>(xn + 4);
            n2 = *reinterpret_cast<const float4*>(xn + 32);
            n3 = *reinterpret_cast<const float4*>(xn + 36);
            stage<8>(Wp + (size_t)(it + 1) * 16384, &Wb[(it + 1) & 1][0], tid);
            asm volatile("s_waitcnt vmcnt(12)" ::: "memory");  // prior X + stage done
        } else {
            asm volatile("s_waitcnt vmcnt(0)" ::: "memory");
        }
        __builtin_amdgcn_s_barrier();  // buf[it&1] staged by all waves
        v8s ah0, al0, ah1, al1;
        split8(x0, x1, ah0, al0);
        split8(x2, x3, ah1, al1);
        const ushort* cb = &Wb[it & 1][0];
        const int s0 = kg ^ swc;
        const int s1 = (32 + kg) ^ swc;
        __builtin_amdgcn_s_setprio(1);
#pragma unroll
        for (int nf = 0; nf < 8; nf++) {
            int rb = (nf * 16 + lane15) * 64;
            v8s bh0 = *reinterpret_cast<const v8s*>(&cb[rb + s0]);
            v8s bl0 = *reinterpret_cast<const v8s*>(&cb[8192 + rb + s0]);
            v8s bh1 = *reinterpret_cast<const v8s*>(&cb[rb + s1]);
            v8s bl1 = *reinterpret_cast<const v8s*>(&cb[8192 + rb + s1]);
            v4f a = acc[nf];
            a = MFMA(ah0, bh0, a, 0, 0, 0);
            a = MFMA(al0, bh0, a, 0, 0, 0);
            a = MFMA(ah0, bl0, a, 0, 0, 0);
            a = MFMA(ah1, bh1, a, 0, 0, 0);
            a = MFMA(al1, bh1, a, 0, 0, 0);
            a = MFMA(ah1, bl1, a, 0, 0, 0);
            acc[nf] = a;
        }
        __builtin_amdgcn_s_setprio(0);
        asm volatile("s_waitcnt lgkmcnt(0)" ::: "memory");  // ds_reads complete
        __builtin_amdgcn_s_barrier();                        // before ring overwrite
        x0 = n0; x1 = n1; x2 = n2; x3 = n3;
    }
#pragma unroll
    for (int nf = 0; nf < 8; nf++) {
        int col = nf * 16 + lane15;
        float bias = B[col];
#pragma unroll
        for (int r = 0; r < 4; r++) {
            int g = brow + wid * 16 + (lane >> 4) * 4 + r;
            if (g < NN) H[(size_t)g * HID + col] = acc[nf][r] + bias;
        }
    }
}

// ---------------- Aggregation: z = h + sum w*h[src] (CSR, 4-way unroll) ----------------

__global__ __launch_bounds__(256) void agg_kernel(const float* __restrict__ h,
                                                  const int* __restrict__ rp,
                                                  const int2* __restrict__ csr,
                                                  float* __restrict__ z) {
    const int node = blockIdx.x * 8 + (threadIdx.x >> 5);
    const int c4 = (threadIdx.x & 31) << 2;
    const float* hp = h + c4;
    v4f a0 = *reinterpret_cast<const v4f*>(hp + (size_t)node * HID);
    v4f a1 = (v4f)0.f, a2 = (v4f)0.f, a3 = (v4f)0.f;
    int k = rp[node];
    const int ke = rp[node + 1];
    for (; k + 3 < ke; k += 4) {
        int2 e0 = csr[k], e1 = csr[k + 1], e2 = csr[k + 2], e3 = csr[k + 3];
        a0 += __int_as_float(e0.y) * *reinterpret_cast<const v4f*>(hp + (size_t)e0.x * HID);
        a1 += __int_as_float(e1.y) * *reinterpret_cast<const v4f*>(hp + (size_t)e1.x * HID);
        a2 += __int_as_float(e2.y) * *reinterpret_cast<const v4f*>(hp + (size_t)e2.x * HID);
        a3 += __int_as_float(e3.y) * *reinterpret_cast<const v4f*>(hp + (size_t)e3.x * HID);
    }
    for (; k < ke; k++) {
        int2 e = csr[k];
        a0 += __int_as_float(e.y) * *reinterpret_cast<const v4f*>(hp + (size_t)e.x * HID);
    }
    *reinterpret_cast<v4f*>(z + (size_t)node * HID + c4) = (a0 + a1) + (a2 + a3);
}

// ---------------- Fused MLP: h = relu(relu(z@W1+b1)@W2+b2) [+ readout] ----------------
// 256 thr / BM=64. 8 W chunks (16KB each) through 2-deep LDS ring, counted
// vmcnt; hidden transposed via per-wave LDS slice (no extra barriers).

template <int LAST>
__global__ __launch_bounds__(256) void mlp_mfma(const float* __restrict__ Z,
                                                const ushort* __restrict__ Wlp,
                                                const float* __restrict__ B1,
                                                const float* __restrict__ B2,
                                                const ushort* __restrict__ RWh,
                                                const ushort* __restrict__ RWl,
                                                const float* __restrict__ RB,
                                                float* __restrict__ H,
                                                float* __restrict__ OUT) {
    __shared__ __align__(16) ushort Wb[2][8192];
    __shared__ __align__(16) ushort Hh[64 * 128];
    __shared__ __align__(16) ushort Hl[64 * 128];
    const int tid = threadIdx.x;
    const int wid = tid >> 6, lane = tid & 63;
    const int lane15 = lane & 15, kg = (lane >> 4) * 8;
    const int swc = (lane15 & 7) << 3;
    const int brow = blockIdx.x * 64;
    const int grow = brow + wid * 16 + lane15;
    const int rowl = wid * 16 + lane15;
    const int sw = (rowl & 7) << 3;

    const float* zr = Z + (size_t)(grow < NN ? grow : 0) * HID + kg;
    float4 za[4], zb[4];
#pragma unroll
    for (int ks = 0; ks < 4; ks++) {
        za[ks] = *reinterpret_cast<const float4*>(zr + ks * 32);
        zb[ks] = *reinterpret_cast<const float4*>(zr + ks * 32 + 4);
    }
    stage<4>(Wlp, &Wb[0][0], tid);

    v8s ah[4], al[4];
    v4f acc[8];
#pragma unroll
    for (int i = 0; i < 8; i++) acc[i] = (v4f)0.f;

    for (int q = 0; q < 8; q++) {
        if (q < 7) {
            stage<4>(Wlp + (size_t)(q + 1) * 8192, &Wb[(q + 1) & 1][0], tid);
            asm volatile("s_waitcnt vmcnt(4)" ::: "memory");
        } else {
            asm volatile("s_waitcnt vmcnt(0)" ::: "memory");
        }
        __builtin_amdgcn_s_barrier();
        if (q == 0) {
#pragma unroll
            for (int ks = 0; ks < 4; ks++) split8(za[ks], zb[ks], ah[ks], al[ks]);
        }
        if (q == 4) {  // reload A-frags from hidden (own wave slice)
#pragma unroll
            for (int ks = 0; ks < 4; ks++) {
                int idx = rowl * 128 + ((ks * 32 + kg) ^ sw);
                ah[ks] = *reinterpret_cast<const v8s*>(&Hh[idx]);
                al[ks] = *reinterpret_cast<const v8s*>(&Hl[idx]);
            }
        }
        const ushort* cb = &Wb[q & 1][0];
        const int nfb = (q & 3) * 2;
        __builtin_amdgcn_s_setprio(1);
#pragma unroll
        for (int t = 0; t < 2; t++) {
            int rb = (t * 16 + lane15) * 128;
            v4f a = acc[nfb + t];
#pragma unroll
            for (int ks = 0; ks < 4; ks++) {
                int s = (ks * 32 + kg) ^ swc;
                v8s bh = *reinterpret_cast<const v8s*>(&cb[rb + s]);
                v8s bl = *reinterpret_cast<const v8s*>(&cb[4096 + rb + s]);
                a = MFMA(ah[ks], bh, a, 0, 0, 0);
                a = MFMA(al[ks], bh, a, 0, 0, 0);
                a = MFMA(ah[ks], bl, a, 0, 0, 0);
            }
            acc[nfb + t] = a;
        }
        __builtin_amdgcn_s_setprio(0);
        if (q < 4) {  // GEMM1 chunk done: bias+relu -> hidden LDS slice
#pragma unroll
            for (int t = 0; t < 2; t++) {
                int nf = nfb + t;
                int col = nf * 16 + lane15;
                float b = B1[col];
#pragma unroll
                for (int r = 0; r < 4; r++) {
                    int rl2 = wid * 16 + (lane >> 4) * 4 + r;
                    float v = acc[nf][r] + b;
                    v = v > 0.f ? v : 0.f;
                    ushort hb = f2bf(v);
                    int idx = rl2 * 128 + (col ^ ((rl2 & 7) << 3));
                    Hh[idx] = hb;
                    Hl[idx] = f2bf(v - bf2f(hb));
                }
                acc[nf] = (v4f)0.f;
            }
        } else if (LAST == 0) {
#pragma unroll
            for (int t = 0; t < 2; t++) {
                int nf = nfb + t;
                int col = nf * 16 + lane15;
                float b = B2[col];
#pragma unroll
                for (int r = 0; r < 4; r++) {
                    int g = brow + wid * 16 + (lane >> 4) * 4 + r;
                    if (g < NN) H[(size_t)g * HID + col] = fmaxf(acc[nf][r] + b, 0.f);
                }
            }
        } else {  // LAST: h3 -> hidden LDS slice for readout
#pragma unroll
            for (int t = 0; t < 2; t++) {
                int nf = nfb + t;
                int col = nf * 16 + lane15;
                float b = B2[col];
#pragma unroll
                for (int r = 0; r < 4; r++) {
                    int rl2 = wid * 16 + (lane >> 4) * 4 + r;
                    float v = fmaxf(acc[nf][r] + b, 0.f);
                    ushort hb = f2bf(v);
                    int idx = rl2 * 128 + (col ^ ((rl2 & 7) << 3));
                    Hh[idx] = hb;
                    Hl[idx] = f2bf(v - bf2f(hb));
                }
            }
        }
        asm volatile("s_waitcnt lgkmcnt(0)" ::: "memory");
        __builtin_amdgcn_s_barrier();
    }

    if (LAST) {
#pragma unroll
        for (int ks = 0; ks < 4; ks++) {
            int idx = rowl * 128 + ((ks * 32 + kg) ^ sw);
            ah[ks] = *reinterpret_cast<const v8s*>(&Hh[idx]);
            al[ks] = *reinterpret_cast<const v8s*>(&Hl[idx]);
        }
        v4f a3[3];
#pragma unroll
        for (int i = 0; i < 3; i++) a3[i] = (v4f)0.f;
#pragma unroll
        for (int nf = 0; nf < 3; nf++) {
            const ushort* bp = RWh + (size_t)(nf * 16 + lane15) * HID + kg;
            const ushort* bq = RWl + (size_t)(nf * 16 + lane15) * HID + kg;
            v4f a = a3[nf];
#pragma unroll
            for (int ks = 0; ks < 4; ks++) {
                v8s bh = *reinterpret_cast<const v8s*>(bp + ks * 32);
                v8s bl = *reinterpret_cast<const v8s*>(bq + ks * 32);
                a = MFMA(ah[ks], bh, a, 0, 0, 0);
                a = MFMA(al[ks], bh, a, 0, 0, 0);
                a = MFMA(ah[ks], bl, a, 0, 0, 0);
            }
            a3[nf] = a;
        }
#pragma unroll
        for (int nf = 0; nf < 3; nf++) {
            int col = nf * 16 + lane15;
            if (col < OUTD) {
                float b = RB[col];
#pragma unroll
                for (int r = 0; r < 4; r++) {
                    int g = brow + wid * 16 + (lane >> 4) * 4 + r;
                    if (g < NN) OUT[(size_t)g * OUTD + col] = a3[nf][r] + b;
                }
            }
        }
    }
}

// ---------------- launch ----------------

extern "C" void kernel_launch(void* const* d_in, const int* in_sizes, int n_in,
                              void* d_out, int out_size, void* d_ws, size_t ws_size,
                              hipStream_t stream) {
    const float* features = (const float*)d_in[0];
    const int* src = (const int*)d_in[1];
    const int* dst = (const int*)d_in[2];
    const float* ew = (const float*)d_in[3];
    const float* embW = (const float*)d_in[4];
    const float* embB = (const float*)d_in[5];
    const float* W1 = (const float*)d_in[6];
    const float* B1 = (const float*)d_in[7];
    const float* W2 = (const float*)d_in[8];
    const float* B2 = (const float*)d_in[9];
    const float* roW = (const float*)d_in[10];
    const float* roB = (const float*)d_in[11];
    float* out = (float*)d_out;

    float* h = (float*)d_ws;                          // NN*HID f32
    float* z = h + (size_t)NN * HID;                  // NN*HID f32
    int* rp = (int*)(z + (size_t)NN * HID);           // NN+16
    int2* csr = (int2*)(rp + NN + 16);                // NE int2
    int* cursor = (int*)(csr + NE);                   // NN
    int* deg = cursor + NN;                           // NN
    int* ex = deg + NN;                               // NN
    int* bsum = ex + NN;                              // NB
    int* bpre = bsum + NB + 4;                        // NB
    ushort* Wemb_p = (ushort*)(bpre + NB + 4);        // 8*16384
    ushort* Wmlp_p = Wemb_p + 8 * 16384;              // NL*8*8192
    ushort* roWt_h = Wmlp_p + (size_t)NL * 8 * 8192;  // 48*128
    ushort* roWt_l = roWt_h + 48 * 128;

    conv_emb<<<256, 256, 0, stream>>>(embW, Wemb_p);
    conv_mlp<<<384, 256, 0, stream>>>(W1, W2, Wmlp_p);
    conv_ro<<<24, 256, 0, stream>>>(roW, roWt_h, roWt_l);

    hipMemsetAsync(deg, 0, NN * sizeof(int), stream);
    count_kernel<<<(NE + 255) / 256, 256, 0, stream>>>(dst, deg);
    scan1<<<NB, 256, 0, stream>>>(deg, ex, bsum);
    scan2<<<1, 256, 0, stream>>>(bsum, bpre);
    scan3<<<NB, 256, 0, stream>>>(deg, ex, bpre, rp, cursor);
    fill_kernel<<<(NE + 255) / 256, 256, 0, stream>>>(src, dst, ew, cursor, csr);

    emb_mfma<<<(NN + 63) / 64, 256, 0, stream>>>(features, Wemb_p, embB, h);

    for (int l = 0; l < NL; l++) {
        agg_kernel<<<NN / 8, 256, 0, stream>>>(h, rp, csr, z);
        const ushort* wl = Wmlp_p + (size_t)l * 8 * 8192;
        const float* b1 = B1 + (size_t)l * HID;
        const float* b2 = B2 + (size_t)l * HID;
        if (l < NL - 1) {
            mlp_mfma<0><<<(NN + 63) / 64, 256, 0, stream>>>(
                z, wl, b1, b2, roWt_h, roWt_l, roB, h, out);
        } else {
            mlp_mfma<1><<<(NN + 63) / 64, 256, 0, stream>>>(
                z, wl, b1, b2, roWt_h, roWt_l, roB, h, out);
        }
    }
}

// Round 9
// 512.352 us; speedup vs baseline: 2.0492x; 1.0536x over previous
//
#include <hip/hip_runtime.h>

#define NN 50000
#define NE 625000
#define IND 512
#define HID 128
#define OUTD 40
#define NL 3
#define NB 196  // ceil(NN/256)

typedef short v8s __attribute__((ext_vector_type(8)));
typedef float v4f __attribute__((ext_vector_type(4)));
typedef const __attribute__((address_space(1))) unsigned int gu32;
typedef __attribute__((address_space(3))) unsigned int lu32;

#define MFMA __builtin_amdgcn_mfma_f32_16x16x32_bf16

__device__ inline ushort f2bf(float x) {
    unsigned u = __float_as_uint(x);
    u += 0x7FFF + ((u >> 16) & 1);  // RNE
    return (ushort)(u >> 16);
}
__device__ inline float bf2f(ushort b) { return __uint_as_float(((unsigned)b) << 16); }

__device__ inline void split8(float4 a, float4 b, v8s& hi, v8s& lo) {
    float v[8] = {a.x, a.y, a.z, a.w, b.x, b.y, b.z, b.w};
    v8s h, l;
#pragma unroll
    for (int i = 0; i < 8; i++) {
        ushort hu = f2bf(v[i]);
        h[i] = (short)hu;
        l[i] = (short)f2bf(v[i] - bf2f(hu));
    }
    hi = h;
    lo = l;
}

// async stage NI*NT*16 bytes from global (linear) into LDS (linear), 16B/lane
template <int NI, int NT>
__device__ inline void stage(const ushort* __restrict__ g, ushort* l, int tid) {
    const int wbase = tid & ~63;
#pragma unroll
    for (int j = 0; j < NI; j++) {
        __builtin_amdgcn_global_load_lds(
            (gu32*)((const char*)g + (size_t)(j * NT + tid) * 16),
            (lu32*)((char*)l + (j * NT + wbase) * 16), 16, 0, 0);
    }
}

// ---------------- CSR build ----------------

__global__ __launch_bounds__(256) void count_kernel(const int* __restrict__ dst,
                                                    int* __restrict__ deg) {
    int e = blockIdx.x * 256 + threadIdx.x;
    if (e < NE) atomicAdd(&deg[dst[e]], 1);
}

// hierarchical scan: (1) per-block exclusive prefix + block sum
__global__ __launch_bounds__(256) void scan1(const int* __restrict__ deg,
                                             int* __restrict__ ex,
                                             int* __restrict__ bsum) {
    __shared__ int s[256];
    int t = threadIdx.x;
    int idx = blockIdx.x * 256 + t;
    int d = idx < NN ? deg[idx] : 0;
    s[t] = d;
    __syncthreads();
#pragma unroll
    for (int off = 1; off < 256; off <<= 1) {
        int v = (t >= off) ? s[t - off] : 0;
        __syncthreads();
        s[t] += v;
        __syncthreads();
    }
    if (idx < NN) ex[idx] = s[t] - d;
    if (t == 255) bsum[blockIdx.x] = s[255];
}

// (2) scan the 196 block sums (single block)
__global__ __launch_bounds__(256) void scan2(const int* __restrict__ bsum,
                                             int* __restrict__ bpre) {
    __shared__ int s[256];
    int t = threadIdx.x;
    int d = t < NB ? bsum[t] : 0;
    s[t] = d;
    __syncthreads();
#pragma unroll
    for (int off = 1; off < 256; off <<= 1) {
        int v = (t >= off) ? s[t - off] : 0;
        __syncthreads();
        s[t] += v;
        __syncthreads();
    }
    if (t < NB) bpre[t] = s[t] - d;
}

// (3) rp/cursor = local prefix + block offset
__global__ __launch_bounds__(256) void scan3(const int* __restrict__ deg,
                                             const int* __restrict__ ex,
                                             const int* __restrict__ bpre,
                                             int* __restrict__ rp,
                                             int* __restrict__ cursor) {
    int idx = blockIdx.x * 256 + threadIdx.x;
    if (idx < NN) {
        int v = ex[idx] + bpre[blockIdx.x];
        rp[idx] = v;
        cursor[idx] = v;
        if (idx == NN - 1) rp[NN] = v + deg[idx];
    }
}

__global__ __launch_bounds__(256) void fill_kernel(const int* __restrict__ src,
                                                   const int* __restrict__ dst,
                                                   const float* __restrict__ ew,
                                                   int* __restrict__ cursor,
                                                   int2* __restrict__ csr) {
    int e = blockIdx.x * 256 + threadIdx.x;
    if (e < NE) {
        int d = dst[e];
        int pos = atomicAdd(&cursor[d], 1);
        csr[pos] = make_int2(src[e], __float_as_int(ew[e]));
    }
}

// ---------------- weight packers: transpose + hi/lo split + baked XOR swizzle ----------------
// emb: P[it=k/64][plane][col][kl^((col&7)<<3)]  (chunk = 16384 ushorts = 32KB)

__global__ __launch_bounds__(256) void conv_emb(const float* __restrict__ W,
                                                ushort* __restrict__ P) {
    int idx = blockIdx.x * 256 + threadIdx.x;  // 512k x 128c
    int k = idx >> 7;
    int c = idx & 127;
    float v = W[(size_t)k * HID + c];
    ushort hb = f2bf(v);
    ushort lb = f2bf(v - bf2f(hb));
    int it = k >> 6, kl = k & 63;
    int pos = it * 16384 + c * 64 + (kl ^ ((c & 7) << 3));
    P[pos] = hb;
    P[pos + 8192] = lb;
}

// mlp: P[l][g][q=c/32][plane][cl][k^((c&7)<<3)]  (chunk = 8192 ushorts = 16KB)
__global__ __launch_bounds__(256) void conv_mlp(const float* __restrict__ W1,
                                                const float* __restrict__ W2,
                                                ushort* __restrict__ P) {
    int idx = blockIdx.x * 256 + threadIdx.x;  // 6 * 128k * 128c
    int lg = idx >> 14;
    int r = idx & 16383;
    int k = r >> 7, c = r & 127;
    int l = lg >> 1, g = lg & 1;
    const float* src = (g ? W2 : W1) + (size_t)l * HID * HID;
    float v = src[(size_t)k * HID + c];
    ushort hb = f2bf(v);
    ushort lb = f2bf(v - bf2f(hb));
    int q = c >> 5, cl = c & 31;
    int pos = lg * 32768 + q * 8192 + cl * 128 + (k ^ ((c & 7) << 3));
    P[pos] = hb;
    P[pos + 4096] = lb;
}

// readout W [128][40] f32 -> padded transposed [48][128] bf16 hi/lo
__global__ __launch_bounds__(256) void conv_ro(const float* __restrict__ W,
                                               ushort* __restrict__ Th,
                                               ushort* __restrict__ Tl) {
    int idx = blockIdx.x * 256 + threadIdx.x;  // 48*128 = 6144
    int c = idx >> 7;
    int kk = idx & 127;
    float v = (c < OUTD) ? W[(size_t)kk * OUTD + c] : 0.f;
    ushort h = f2bf(v);
    Th[idx] = h;
    Tl[idx] = f2bf(v - bf2f(h));
}

// ---------------- Embedding GEMM: [NN,512]@[512,128]+b ----------------
// 512 thr = 8 waves / BM=128. W chunks (32KB) async-staged into 2-deep LDS
// ring with counted vmcnt; X per-lane register loads prefetched 1 chunk ahead.
// 64KB LDS -> 2 blocks/CU = 16 waves/CU.

__global__ __launch_bounds__(512) void emb_mfma(const float* __restrict__ X,
                                                const ushort* __restrict__ Wp,
                                                const float* __restrict__ B,
                                                float* __restrict__ H) {
    __shared__ __align__(16) ushort Wb[2][16384];
    const int tid = threadIdx.x;
    const int wid = tid >> 6, lane = tid & 63;
    const int lane15 = lane & 15, kg = (lane >> 4) * 8;
    const int swc = (lane15 & 7) << 3;
    const int brow = blockIdx.x * 128;
    const int grow = brow + wid * 16 + lane15;
    const float* xr = X + (size_t)(grow < NN ? grow : 0) * IND + kg;

    v4f acc[8];
#pragma unroll
    for (int i = 0; i < 8; i++) acc[i] = (v4f)0.f;

    float4 x0 = *reinterpret_cast<const float4*>(xr);
    float4 x1 = *reinterpret_cast<const float4*>(xr + 4);
    float4 x2 = *reinterpret_cast<const float4*>(xr + 32);
    float4 x3 = *reinterpret_cast<const float4*>(xr + 36);
    stage<4, 512>(Wp, &Wb[0][0], tid);

    for (int it = 0; it < 8; ++it) {
        float4 n0, n1, n2, n3;
        if (it < 7) {
            const float* xn = xr + (it + 1) * 64;
            n0 = *reinterpret_cast<const float4*>(xn);
            n1 = *reinterpret_cast<const float4*>(xn + 4);
            n2 = *reinterpret_cast<const float4*>(xn + 32);
            n3 = *reinterpret_cast<const float4*>(xn + 36);
            stage<4, 512>(Wp + (size_t)(it + 1) * 16384, &Wb[(it + 1) & 1][0], tid);
            asm volatile("s_waitcnt vmcnt(8)" ::: "memory");  // prior X + stage done
        } else {
            asm volatile("s_waitcnt vmcnt(0)" ::: "memory");
        }
        __builtin_amdgcn_s_barrier();  // buf[it&1] staged by all waves
        v8s ah0, al0, ah1, al1;
        split8(x0, x1, ah0, al0);
        split8(x2, x3, ah1, al1);
        const ushort* cb = &Wb[it & 1][0];
        const int s0 = kg ^ swc;
        const int s1 = (32 + kg) ^ swc;
        __builtin_amdgcn_s_setprio(1);
#pragma unroll
        for (int nf = 0; nf < 8; nf++) {
            int rb = (nf * 16 + lane15) * 64;
            v8s bh0 = *reinterpret_cast<const v8s*>(&cb[rb + s0]);
            v8s bl0 = *reinterpret_cast<const v8s*>(&cb[8192 + rb + s0]);
            v8s bh1 = *reinterpret_cast<const v8s*>(&cb[rb + s1]);
            v8s bl1 = *reinterpret_cast<const v8s*>(&cb[8192 + rb + s1]);
            v4f a = acc[nf];
            a = MFMA(ah0, bh0, a, 0, 0, 0);
            a = MFMA(al0, bh0, a, 0, 0, 0);
            a = MFMA(ah0, bl0, a, 0, 0, 0);
            a = MFMA(ah1, bh1, a, 0, 0, 0);
            a = MFMA(al1, bh1, a, 0, 0, 0);
            a = MFMA(ah1, bl1, a, 0, 0, 0);
            acc[nf] = a;
        }
        __builtin_amdgcn_s_setprio(0);
        asm volatile("s_waitcnt lgkmcnt(0)" ::: "memory");  // ds_reads complete
        __builtin_amdgcn_s_barrier();                        // before ring overwrite
        x0 = n0; x1 = n1; x2 = n2; x3 = n3;
    }
#pragma unroll
    for (int nf = 0; nf < 8; nf++) {
        int col = nf * 16 + lane15;
        float bias = B[col];
#pragma unroll
        for (int r = 0; r < 4; r++) {
            int g = brow + wid * 16 + (lane >> 4) * 4 + r;
            if (g < NN) H[(size_t)g * HID + col] = acc[nf][r] + bias;
        }
    }
}

// ---------------- Aggregation: z = h + sum w*h[src] (CSR, 8 in flight) ----------------

__global__ __launch_bounds__(256) void agg_kernel(const float* __restrict__ h,
                                                  const int* __restrict__ rp,
                                                  const int2* __restrict__ csr,
                                                  float* __restrict__ z) {
    const int node = blockIdx.x * 8 + (threadIdx.x >> 5);
    const int c4 = (threadIdx.x & 31) << 2;
    const float* hp = h + c4;
    v4f a0 = *reinterpret_cast<const v4f*>(hp + (size_t)node * HID);
    v4f a1 = (v4f)0.f, a2 = (v4f)0.f, a3 = (v4f)0.f;
    int k = rp[node];
    const int ke = rp[node + 1];
    for (; k + 7 < ke; k += 8) {
        int2 e0 = csr[k], e1 = csr[k + 1], e2 = csr[k + 2], e3 = csr[k + 3];
        int2 e4 = csr[k + 4], e5 = csr[k + 5], e6 = csr[k + 6], e7 = csr[k + 7];
        const v4f v0 = *reinterpret_cast<const v4f*>(hp + (size_t)e0.x * HID);
        const v4f v1 = *reinterpret_cast<const v4f*>(hp + (size_t)e1.x * HID);
        const v4f v2 = *reinterpret_cast<const v4f*>(hp + (size_t)e2.x * HID);
        const v4f v3 = *reinterpret_cast<const v4f*>(hp + (size_t)e3.x * HID);
        const v4f v4 = *reinterpret_cast<const v4f*>(hp + (size_t)e4.x * HID);
        const v4f v5 = *reinterpret_cast<const v4f*>(hp + (size_t)e5.x * HID);
        const v4f v6 = *reinterpret_cast<const v4f*>(hp + (size_t)e6.x * HID);
        const v4f v7 = *reinterpret_cast<const v4f*>(hp + (size_t)e7.x * HID);
        a0 += __int_as_float(e0.y) * v0;
        a1 += __int_as_float(e1.y) * v1;
        a2 += __int_as_float(e2.y) * v2;
        a3 += __int_as_float(e3.y) * v3;
        a0 += __int_as_float(e4.y) * v4;
        a1 += __int_as_float(e5.y) * v5;
        a2 += __int_as_float(e6.y) * v6;
        a3 += __int_as_float(e7.y) * v7;
    }
    for (; k + 1 < ke; k += 2) {
        int2 e0 = csr[k], e1 = csr[k + 1];
        a0 += __int_as_float(e0.y) * *reinterpret_cast<const v4f*>(hp + (size_t)e0.x * HID);
        a1 += __int_as_float(e1.y) * *reinterpret_cast<const v4f*>(hp + (size_t)e1.x * HID);
    }
    if (k < ke) {
        int2 e = csr[k];
        a0 += __int_as_float(e.y) * *reinterpret_cast<const v4f*>(hp + (size_t)e.x * HID);
    }
    *reinterpret_cast<v4f*>(z + (size_t)node * HID + c4) = (a0 + a1) + (a2 + a3);
}

// ---------------- Fused MLP: h = relu(relu(z@W1+b1)@W2+b2) [+ readout] ----------------
// 256 thr / BM=64. 8 W chunks (16KB) through 3-deep LDS ring (prefetch depth
// 2, vmcnt(8)); hidden transposed via per-wave LDS slice. 80KB -> 2 blk/CU.

template <int LAST>
__global__ __launch_bounds__(256) void mlp_mfma(const float* __restrict__ Z,
                                                const ushort* __restrict__ Wlp,
                                                const float* __restrict__ B1,
                                                const float* __restrict__ B2,
                                                const ushort* __restrict__ RWh,
                                                const ushort* __restrict__ RWl,
                                                const float* __restrict__ RB,
                                                float* __restrict__ H,
                                                float* __restrict__ OUT) {
    __shared__ __align__(16) ushort Wb[3][8192];
    __shared__ __align__(16) ushort Hh[64 * 128];
    __shared__ __align__(16) ushort Hl[64 * 128];
    const int tid = threadIdx.x;
    const int wid = tid >> 6, lane = tid & 63;
    const int lane15 = lane & 15, kg = (lane >> 4) * 8;
    const int swc = (lane15 & 7) << 3;
    const int brow = blockIdx.x * 64;
    const int grow = brow + wid * 16 + lane15;
    const int rowl = wid * 16 + lane15;
    const int sw = (rowl & 7) << 3;

    const float* zr = Z + (size_t)(grow < NN ? grow : 0) * HID + kg;
    float4 za[4], zb[4];
#pragma unroll
    for (int ks = 0; ks < 4; ks++) {
        za[ks] = *reinterpret_cast<const float4*>(zr + ks * 32);
        zb[ks] = *reinterpret_cast<const float4*>(zr + ks * 32 + 4);
    }
    stage<4, 256>(Wlp, &Wb[0][0], tid);
    stage<4, 256>(Wlp + 8192, &Wb[1][0], tid);

    v8s ah[4], al[4];
    v4f acc[8];
#pragma unroll
    for (int i = 0; i < 8; i++) acc[i] = (v4f)0.f;

#pragma unroll
    for (int q = 0; q < 8; q++) {
        if (q < 6) {
            stage<4, 256>(Wlp + (size_t)(q + 2) * 8192, &Wb[(q + 2) % 3][0], tid);
            asm volatile("s_waitcnt vmcnt(8)" ::: "memory");
        } else if (q == 6) {
            asm volatile("s_waitcnt vmcnt(4)" ::: "memory");
        } else {
            asm volatile("s_waitcnt vmcnt(0)" ::: "memory");
        }
        __builtin_amdgcn_s_barrier();
        if (q == 0) {
#pragma unroll
            for (int ks = 0; ks < 4; ks++) split8(za[ks], zb[ks], ah[ks], al[ks]);
        }
        if (q == 4) {  // reload A-frags from hidden (own wave slice)
#pragma unroll
            for (int ks = 0; ks < 4; ks++) {
                int idx = rowl * 128 + ((ks * 32 + kg) ^ sw);
                ah[ks] = *reinterpret_cast<const v8s*>(&Hh[idx]);
                al[ks] = *reinterpret_cast<const v8s*>(&Hl[idx]);
            }
        }
        const ushort* cb = &Wb[q % 3][0];
        const int nfb = (q & 3) * 2;
        __builtin_amdgcn_s_setprio(1);
#pragma unroll
        for (int t = 0; t < 2; t++) {
            int rb = (t * 16 + lane15) * 128;
            v4f a = acc[nfb + t];
#pragma unroll
            for (int ks = 0; ks < 4; ks++) {
                int s = (ks * 32 + kg) ^ swc;
                v8s bh = *reinterpret_cast<const v8s*>(&cb[rb + s]);
                v8s bl = *reinterpret_cast<const v8s*>(&cb[4096 + rb + s]);
                a = MFMA(ah[ks], bh, a, 0, 0, 0);
                a = MFMA(al[ks], bh, a, 0, 0, 0);
                a = MFMA(ah[ks], bl, a, 0, 0, 0);
            }
            acc[nfb + t] = a;
        }
        __builtin_amdgcn_s_setprio(0);
        if (q < 4) {  // GEMM1 chunk done: bias+relu -> hidden LDS slice
#pragma unroll
            for (int t = 0; t < 2; t++) {
                int nf = nfb + t;
                int col = nf * 16 + lane15;
                float b = B1[col];
#pragma unroll
                for (int r = 0; r < 4; r++) {
                    int rl2 = wid * 16 + (lane >> 4) * 4 + r;
                    float v = acc[nf][r] + b;
                    v = v > 0.f ? v : 0.f;
                    ushort hb = f2bf(v);
                    int idx = rl2 * 128 + (col ^ ((rl2 & 7) << 3));
                    Hh[idx] = hb;
                    Hl[idx] = f2bf(v - bf2f(hb));
                }
                acc[nf] = (v4f)0.f;
            }
        } else if (LAST == 0) {
#pragma unroll
            for (int t = 0; t < 2; t++) {
                int nf = nfb + t;
                int col = nf * 16 + lane15;
                float b = B2[col];
#pragma unroll
                for (int r = 0; r < 4; r++) {
                    int g = brow + wid * 16 + (lane >> 4) * 4 + r;
                    if (g < NN) H[(size_t)g * HID + col] = fmaxf(acc[nf][r] + b, 0.f);
                }
            }
        } else {  // LAST: h3 -> hidden LDS slice for readout
#pragma unroll
            for (int t = 0; t < 2; t++) {
                int nf = nfb + t;
                int col = nf * 16 + lane15;
                float b = B2[col];
#pragma unroll
                for (int r = 0; r < 4; r++) {
                    int rl2 = wid * 16 + (lane >> 4) * 4 + r;
                    float v = fmaxf(acc[nf][r] + b, 0.f);
                    ushort hb = f2bf(v);
                    int idx = rl2 * 128 + (col ^ ((rl2 & 7) << 3));
                    Hh[idx] = hb;
                    Hl[idx] = f2bf(v - bf2f(hb));
                }
            }
        }
        asm volatile("s_waitcnt lgkmcnt(0)" ::: "memory");
        __builtin_amdgcn_s_barrier();
    }

    if (LAST) {
#pragma unroll
        for (int ks = 0; ks < 4; ks++) {
            int idx = rowl * 128 + ((ks * 32 + kg) ^ sw);
            ah[ks] = *reinterpret_cast<const v8s*>(&Hh[idx]);
            al[ks] = *reinterpret_cast<const v8s*>(&Hl[idx]);
        }
        v4f a3[3];
#pragma unroll
        for (int i = 0; i < 3; i++) a3[i] = (v4f)0.f;
#pragma unroll
        for (int nf = 0; nf < 3; nf++) {
            const ushort* bp = RWh + (size_t)(nf * 16 + lane15) * HID + kg;
            const ushort* bq = RWl + (size_t)(nf * 16 + lane15) * HID + kg;
            v4f a = a3[nf];
#pragma unroll
            for (int ks = 0; ks < 4; ks++) {
                v8s bh = *reinterpret_cast<const v8s*>(bp + ks * 32);
                v8s bl = *reinterpret_cast<const v8s*>(bq + ks * 32);
                a = MFMA(ah[ks], bh, a, 0, 0, 0);
                a = MFMA(al[ks], bh, a, 0, 0, 0);
                a = MFMA(ah[ks], bl, a, 0, 0, 0);
            }
            a3[nf] = a;
        }
#pragma unroll
        for (int nf = 0; nf < 3; nf++) {
            int col = nf * 16 + lane15;
            if (col < OUTD) {
                float b = RB[col];
#pragma unroll
                for (int r = 0; r < 4; r++) {
                    int g = brow + wid * 16 + (lane >> 4) * 4 + r;
                    if (g < NN) OUT[(size_t)g * OUTD + col] = a3[nf][r] + b;
                }
            }
        }
    }
}

// ---------------- launch ----------------

extern "C" void kernel_launch(void* const* d_in, const int* in_sizes, int n_in,
                              void* d_out, int out_size, void* d_ws, size_t ws_size,
                              hipStream_t stream) {
    const float* features = (const float*)d_in[0];
    const int* src = (const int*)d_in[1];
    const int* dst = (const int*)d_in[2];
    const float* ew = (const float*)d_in[3];
    const float* embW = (const float*)d_in[4];
    const float* embB = (const float*)d_in[5];
    const float* W1 = (const float*)d_in[6];
    const float* B1 = (const float*)d_in[7];
    const float* W2 = (const float*)d_in[8];
    const float* B2 = (const float*)d_in[9];
    const float* roW = (const float*)d_in[10];
    const float* roB = (const float*)d_in[11];
    float* out = (float*)d_out;

    float* h = (float*)d_ws;                          // NN*HID f32
    float* z = h + (size_t)NN * HID;                  // NN*HID f32
    int* rp = (int*)(z + (size_t)NN * HID);           // NN+16
    int2* csr = (int2*)(rp + NN + 16);                // NE int2
    int* cursor = (int*)(csr + NE);                   // NN
    int* deg = cursor + NN;                           // NN
    int* ex = deg + NN;                               // NN
    int* bsum = ex + NN;                              // NB
    int* bpre = bsum + NB + 4;                        // NB
    ushort* Wemb_p = (ushort*)(bpre + NB + 4);        // 8*16384
    ushort* Wmlp_p = Wemb_p + 8 * 16384;              // NL*8*8192
    ushort* roWt_h = Wmlp_p + (size_t)NL * 8 * 8192;  // 48*128
    ushort* roWt_l = roWt_h + 48 * 128;

    conv_emb<<<256, 256, 0, stream>>>(embW, Wemb_p);
    conv_mlp<<<384, 256, 0, stream>>>(W1, W2, Wmlp_p);
    conv_ro<<<24, 256, 0, stream>>>(roW, roWt_h, roWt_l);

    hipMemsetAsync(deg, 0, NN * sizeof(int), stream);
    count_kernel<<<(NE + 255) / 256, 256, 0, stream>>>(dst, deg);
    scan1<<<NB, 256, 0, stream>>>(deg, ex, bsum);
    scan2<<<1, 256, 0, stream>>>(bsum, bpre);
    scan3<<<NB, 256, 0, stream>>>(deg, ex, bpre, rp, cursor);
    fill_kernel<<<(NE + 255) / 256, 256, 0, stream>>>(src, dst, ew, cursor, csr);

    emb_mfma<<<(NN + 127) / 128, 512, 0, stream>>>(features, Wemb_p, embB, h);

    for (int l = 0; l < NL; l++) {
        agg_kernel<<<NN / 8, 256, 0, stream>>>(h, rp, csr, z);
        const ushort* wl = Wmlp_p + (size_t)l * 8 * 8192;
        const float* b1 = B1 + (size_t)l * HID;
        const float* b2 = B2 + (size_t)l * HID;
        if (l < NL - 1) {
            mlp_mfma<0><<<(NN + 63) / 64, 256, 0, stream>>>(
                z, wl, b1, b2, roWt_h, roWt_l, roB, h, out);
        } else {
            mlp_mfma<1><<<(NN + 63) / 64, 256, 0, stream>>>(
                z, wl, b1, b2, roWt_h, roWt_l, roB, h, out);
        }
    }
}